// Round 1
// baseline (10007.829 us; speedup 1.0000x reference)
//
#include <hip/hip_runtime.h>
#include <hip/hip_bf16.h>
#include <math.h>

// Problem dims
#define B_  32
#define T1_ 128
#define L1_ 543
#define C1_ 3
#define F1_ 64     // filters stage1, gates G1=256
#define T2_ 543
#define L2_ 64
#define F2_ 32     // filters stage2, gates G2=128
#define D_  32
#define S_  64
#define FF_ 64
#define VOCAB_ 32000

__device__ __forceinline__ float sigmoidf_(float x){ return 1.0f/(1.0f + expf(-x)); }

// ---------------- Stage 1: ConvLSTM1D #1, one launch per timestep ----------------
// grid (34, 32), block 256. tid = f(64) + 64*lq(4). Each thread: 4 l-positions, 4 gates.
__global__ __launch_bounds__(256) void lstm1_step(
    const float* __restrict__ x,    // (B,T1,L1,3)
    const float* __restrict__ Wx,   // (3,3,256)
    const float* __restrict__ Wh,   // (3,64,256)
    const float* __restrict__ bias, // (256)
    const float* __restrict__ h_in, // (B,L1,64)
    float* __restrict__ h_out,      // (B,L1,64)
    float* __restrict__ cst,        // (B,L1,64) in/out
    int t)
{
    __shared__ float sh[18][64];    // h rows l0-1 .. l0+16
    __shared__ float sxx[18][3];
    const int f  = threadIdx.x & 63;
    const int lq = threadIdx.x >> 6;
    const int b  = blockIdx.y;
    const int l0 = blockIdx.x * 16;

    const float* hb = h_in + (size_t)b * (L1_*F1_);
    for (int i = threadIdx.x; i < 18*64; i += 256) {
        int r = i >> 6, c = i & 63;
        int l = l0 - 1 + r;
        sh[r][c] = (l >= 0 && l < L1_) ? hb[l*64 + c] : 0.0f;
    }
    const float* xb = x + ((size_t)b*T1_ + t) * (L1_*C1_);
    for (int i = threadIdx.x; i < 54; i += 256) {
        int r = i / 3, c = i - r*3;
        int l = l0 - 1 + r;
        sxx[r][c] = (l >= 0 && l < L1_) ? xb[l*3 + c] : 0.0f;
    }
    __syncthreads();

    float zi[4], zf[4], zg[4], zo[4];
    {
        float b0 = bias[f], b1v = bias[64+f], b2v = bias[128+f], b3v = bias[192+f];
        #pragma unroll
        for (int il=0; il<4; ++il){ zi[il]=b0; zf[il]=b1v; zg[il]=b2v; zo[il]=b3v; }
    }
    // input conv (K=3 taps x 3 ch)
    #pragma unroll
    for (int k=0; k<3; ++k)
      #pragma unroll
      for (int c=0; c<3; ++c){
        const float* wp = Wx + (k*3+c)*256;
        float wi = wp[f], wf = wp[64+f], wg = wp[128+f], wo = wp[192+f];
        #pragma unroll
        for (int il=0; il<4; ++il){
          float xv = sxx[lq*4+il + k][c];
          zi[il] = fmaf(xv, wi, zi[il]);
          zf[il] = fmaf(xv, wf, zf[il]);
          zg[il] = fmaf(xv, wg, zg[il]);
          zo[il] = fmaf(xv, wo, zo[il]);
        }
      }
    // recurrent conv (K=3 taps x 64 ch)
    for (int k=0; k<3; ++k)
      for (int c=0; c<64; ++c){
        const float* wp = Wh + (k*64+c)*256;
        float wi = wp[f], wf = wp[64+f], wg = wp[128+f], wo = wp[192+f];
        #pragma unroll
        for (int il=0; il<4; ++il){
          float hv = sh[lq*4+il + k][c];
          zi[il] = fmaf(hv, wi, zi[il]);
          zf[il] = fmaf(hv, wf, zf[il]);
          zg[il] = fmaf(hv, wg, zg[il]);
          zo[il] = fmaf(hv, wo, zo[il]);
        }
      }
    // gate nonlinearities + state update (Keras order i,f,g,o; relu cell act)
    #pragma unroll
    for (int il=0; il<4; ++il){
        int l = l0 + lq*4 + il;
        if (l < L1_) {
            size_t idx = (size_t)b*(L1_*F1_) + (size_t)l*64 + f;
            float cv = cst[idx];
            float iv = sigmoidf_(zi[il]);
            float fv = sigmoidf_(zf[il]);
            float gv = fmaxf(zg[il], 0.0f);
            float ov = sigmoidf_(zo[il]);
            cv = fv*cv + iv*gv;
            cst[idx] = cv;
            h_out[idx] = ov * fmaxf(cv, 0.0f);
        }
    }
}

// ---------------- Stage 2: ConvLSTM1D #2, persistent, 1 workgroup per batch ----------------
// grid (32), block 256. tid = f(32) + 32*lq(8). Each thread: 8 l-positions, 4 gates, c-state in regs.
__global__ __launch_bounds__(256) void lstm2_all(
    const float* __restrict__ x2,   // (B, 543, 64) = stage1 final h
    const float* __restrict__ Wx,   // (3,1,128)
    const float* __restrict__ Wh,   // (3,32,128)
    const float* __restrict__ bias, // (128)
    float* __restrict__ out)        // (B, 64, 32)
{
    __shared__ float swh[3*32*128]; // 48 KB, whole recurrent weight resident
    __shared__ float swx[3*128];
    __shared__ float sb[128];
    __shared__ float sh2[66][32];   // h with zero halo rows 0,65
    __shared__ float sxr[66];       // x row with zero halo

    const int b  = blockIdx.x;
    const int f  = threadIdx.x & 31;
    const int lq = threadIdx.x >> 5;

    for (int i=threadIdx.x; i<3*32*128; i+=256) swh[i] = Wh[i];
    for (int i=threadIdx.x; i<3*128;    i+=256) swx[i] = Wx[i];
    for (int i=threadIdx.x; i<128;      i+=256) sb[i]  = bias[i];
    for (int i=threadIdx.x; i<66*32;    i+=256) (&sh2[0][0])[i] = 0.0f;
    if (threadIdx.x < 66) sxr[threadIdx.x] = 0.0f;

    float creg[8];
    #pragma unroll
    for (int il=0; il<8; ++il) creg[il]=0.0f;

    __syncthreads();

    const float* xb = x2 + (size_t)b * (T2_*L2_);
    const float bi0 = sb[f], bf0 = sb[32+f], bg0 = sb[64+f], bo0 = sb[96+f];

    for (int t=0; t<T2_; ++t){
        if (threadIdx.x < 64) sxr[1+threadIdx.x] = xb[t*64 + threadIdx.x];
        __syncthreads();

        float zi[8], zf[8], zg[8], zo[8];
        #pragma unroll
        for (int il=0; il<8; ++il){ zi[il]=bi0; zf[il]=bf0; zg[il]=bg0; zo[il]=bo0; }

        #pragma unroll
        for (int k=0; k<3; ++k){
            float wi = swx[k*128+f], wf = swx[k*128+32+f], wg = swx[k*128+64+f], wo = swx[k*128+96+f];
            #pragma unroll
            for (int il=0; il<8; ++il){
                float xv = sxr[lq*8+il + k];
                zi[il]=fmaf(xv,wi,zi[il]); zf[il]=fmaf(xv,wf,zf[il]);
                zg[il]=fmaf(xv,wg,zg[il]); zo[il]=fmaf(xv,wo,zo[il]);
            }
        }
        for (int k=0; k<3; ++k)
          for (int c=0; c<32; ++c){
            const float* wp = swh + (k*32+c)*128;
            float wi = wp[f], wf = wp[32+f], wg = wp[64+f], wo = wp[96+f];
            #pragma unroll
            for (int il=0; il<8; ++il){
                float hv = sh2[lq*8+il + k][c];
                zi[il]=fmaf(hv,wi,zi[il]); zf[il]=fmaf(hv,wf,zf[il]);
                zg[il]=fmaf(hv,wg,zg[il]); zo[il]=fmaf(hv,wo,zo[il]);
            }
          }
        __syncthreads();   // all sh2 reads done before overwrite
        #pragma unroll
        for (int il=0; il<8; ++il){
            float iv = sigmoidf_(zi[il]);
            float fv = sigmoidf_(zf[il]);
            float gv = fmaxf(zg[il],0.0f);
            float ov = sigmoidf_(zo[il]);
            creg[il] = fv*creg[il] + iv*gv;
            sh2[1 + lq*8 + il][f] = ov * fmaxf(creg[il], 0.0f);
        }
        __syncthreads();
    }
    #pragma unroll
    for (int il=0; il<8; ++il){
        int l = lq*8+il;
        out[(size_t)b*(64*32) + l*32 + f] = sh2[1+l][f];
    }
}

// ---------------- Transformer decoder, 1 workgroup per batch ----------------
__global__ __launch_bounds__(256) void decoder_kernel(
    const float* __restrict__ xin,  // (B,64,32)
    const float* __restrict__ Wq, const float* __restrict__ bq,
    const float* __restrict__ Wk, const float* __restrict__ bk,
    const float* __restrict__ Wv, const float* __restrict__ bv,
    const float* __restrict__ Wo, const float* __restrict__ bo,
    const float* __restrict__ g1, const float* __restrict__ be1,
    const float* __restrict__ W1, const float* __restrict__ bf1,
    const float* __restrict__ W2, const float* __restrict__ bf2,
    const float* __restrict__ g2, const float* __restrict__ be2,
    float* __restrict__ xout)       // (B,64,32)
{
    __shared__ float smem[16384];   // 64 KB, manually partitioned
    float* sx  = smem;              // 2048: input x (later reused for pre-LN2)
    float* sq  = smem + 2048;
    float* sk  = smem + 4096;
    float* sv  = smem + 6144;
    float* so  = smem + 8192;       // attention out (pre-proj)
    float* sy  = smem + 10240;      // LN1 output
    float* sff = smem + 12288;      // 4096: FFN hidden

    const int b = blockIdx.x;
    const int tid = threadIdx.x;

    for (int i=tid; i<2048; i+=256) sx[i] = xin[(size_t)b*2048 + i];
    __syncthreads();

    // QKV projections: j = h*16+kk flat (weights (D,H,K) are contiguous in j)
    for (int i=tid; i<2048; i+=256){
        int s = i >> 5, j = i & 31;
        float aq = bq[j], ak = bk[j], av = bv[j];
        for (int d=0; d<32; ++d){
            float xv = sx[s*32+d];
            aq = fmaf(xv, Wq[d*32+j], aq);
            ak = fmaf(xv, Wk[d*32+j], ak);
            av = fmaf(xv, Wv[d*32+j], av);
        }
        sq[i]=aq; sk[i]=ak; sv[i]=av;
    }
    __syncthreads();

    // causal attention: one thread per (head, query row); two-pass (max, then exp+PV)
    if (tid < 128){
        int h = tid >> 6, si = tid & 63;
        const int o = h*16;
        float qv[16];
        #pragma unroll
        for (int kk=0; kk<16; ++kk) qv[kk] = sq[si*32 + o + kk];
        float mx = -1e30f;
        for (int ti=0; ti<=si; ++ti){
            float sc = 0.f;
            #pragma unroll
            for (int kk=0; kk<16; ++kk) sc = fmaf(qv[kk], sk[ti*32+o+kk], sc);
            mx = fmaxf(mx, sc*0.25f);
        }
        float sum = 0.f;
        float acc[16];
        #pragma unroll
        for (int kk=0; kk<16; ++kk) acc[kk]=0.f;
        for (int ti=0; ti<=si; ++ti){
            float sc = 0.f;
            #pragma unroll
            for (int kk=0; kk<16; ++kk) sc = fmaf(qv[kk], sk[ti*32+o+kk], sc);
            float p = expf(sc*0.25f - mx);
            sum += p;
            #pragma unroll
            for (int kk=0; kk<16; ++kk) acc[kk] = fmaf(p, sv[ti*32+o+kk], acc[kk]);
        }
        float inv = 1.f/sum;
        #pragma unroll
        for (int kk=0; kk<16; ++kk) so[si*32 + o + kk] = acc[kk]*inv;
    }
    __syncthreads();

    // output projection + residual
    for (int i=tid; i<2048; i+=256){
        int s = i>>5, d = i&31;
        float a = bo[d];
        for (int j=0; j<32; ++j) a = fmaf(so[s*32+j], Wo[j*32+d], a);
        sy[i] = sx[i] + a;
    }
    __syncthreads();
    // LN1 (one thread per row)
    if (tid < 64){
        float mu=0.f;
        for (int d=0; d<32; ++d) mu += sy[tid*32+d];
        mu *= (1.f/32.f);
        float var=0.f;
        for (int d=0; d<32; ++d){ float dd = sy[tid*32+d]-mu; var = fmaf(dd,dd,var); }
        var *= (1.f/32.f);
        float rs = rsqrtf(var + 1e-5f);
        for (int d=0; d<32; ++d) sy[tid*32+d] = (sy[tid*32+d]-mu)*rs*g1[d] + be1[d];
    }
    __syncthreads();
    // FFN up (relu)
    for (int i=tid; i<4096; i+=256){
        int s = i>>6, ff = i&63;
        float a = bf1[ff];
        for (int d=0; d<32; ++d) a = fmaf(sy[s*32+d], W1[d*64+ff], a);
        sff[i] = fmaxf(a, 0.f);
    }
    __syncthreads();
    // FFN down + residual -> sx (reuse)
    for (int i=tid; i<2048; i+=256){
        int s=i>>5, d=i&31;
        float a = bf2[d];
        for (int ff=0; ff<64; ++ff) a = fmaf(sff[s*64+ff], W2[ff*32+d], a);
        sx[i] = sy[i] + a;
    }
    __syncthreads();
    // LN2 + write out
    if (tid < 64){
        float mu=0.f;
        for (int d=0; d<32; ++d) mu += sx[tid*32+d];
        mu *= (1.f/32.f);
        float var=0.f;
        for (int d=0; d<32; ++d){ float dd = sx[tid*32+d]-mu; var = fmaf(dd,dd,var); }
        var *= (1.f/32.f);
        float rs = rsqrtf(var + 1e-5f);
        for (int d=0; d<32; ++d)
            xout[(size_t)b*2048 + tid*32 + d] = (sx[tid*32+d]-mu)*rs*g2[d] + be2[d];
    }
}

// ---------------- Vocab head: (2048,32) @ (32,32000) + bd ----------------
// grid (63, 128), block 256. Block: 16 rows x 512 cols; thread: 16 rows x 2 cols (float2 stores).
__global__ __launch_bounds__(256) void head_kernel(
    const float* __restrict__ xin,  // (2048, 32)
    const float* __restrict__ Wd,   // (32, 32000)
    const float* __restrict__ bd,   // (32000)
    float* __restrict__ out)        // (2048, 32000)
{
    __shared__ float sxr[16*32];
    const int r0 = blockIdx.y * 16;
    const int c0 = blockIdx.x * 512;
    const int tid = threadIdx.x;
    for (int i=tid; i<512; i+=256) sxr[i] = xin[(size_t)(r0 + (i>>5))*32 + (i&31)];
    __syncthreads();
    int c = c0 + tid*2;
    if (c >= VOCAB_) return;
    float a0[16], a1[16];
    float b0 = bd[c], b1 = bd[c+1];
    #pragma unroll
    for (int r=0; r<16; ++r){ a0[r]=b0; a1[r]=b1; }
    for (int d=0; d<32; ++d){
        float w0 = Wd[(size_t)d*VOCAB_ + c];
        float w1 = Wd[(size_t)d*VOCAB_ + c + 1];
        #pragma unroll
        for (int r=0; r<16; ++r){
            float xv = sxr[r*32+d];
            a0[r] = fmaf(xv, w0, a0[r]);
            a1[r] = fmaf(xv, w1, a1[r]);
        }
    }
    #pragma unroll
    for (int r=0; r<16; ++r){
        float2 v = make_float2(a0[r], a1[r]);
        *reinterpret_cast<float2*>(&out[(size_t)(r0+r)*VOCAB_ + c]) = v;
    }
}

// ---------------- launch ----------------
extern "C" void kernel_launch(void* const* d_in, const int* in_sizes, int n_in,
                              void* d_out, int out_size, void* d_ws, size_t ws_size,
                              hipStream_t stream)
{
    const float* x   = (const float*)d_in[0];
    const float* Wx1 = (const float*)d_in[1];
    const float* Wh1 = (const float*)d_in[2];
    const float* b1  = (const float*)d_in[3];
    const float* Wx2 = (const float*)d_in[4];
    const float* Wh2 = (const float*)d_in[5];
    const float* b2  = (const float*)d_in[6];
    const float* Wq  = (const float*)d_in[7];
    const float* bq  = (const float*)d_in[8];
    const float* Wk  = (const float*)d_in[9];
    const float* bk  = (const float*)d_in[10];
    const float* Wv  = (const float*)d_in[11];
    const float* bv  = (const float*)d_in[12];
    const float* Wo  = (const float*)d_in[13];
    const float* bo  = (const float*)d_in[14];
    const float* g1  = (const float*)d_in[15];
    const float* be1 = (const float*)d_in[16];
    const float* W1  = (const float*)d_in[17];
    const float* bf1 = (const float*)d_in[18];
    const float* W2  = (const float*)d_in[19];
    const float* bf2 = (const float*)d_in[20];
    const float* g2  = (const float*)d_in[21];
    const float* be2 = (const float*)d_in[22];
    const float* Wd  = (const float*)d_in[23];
    const float* bd  = (const float*)d_in[24];

    const size_t nH = (size_t)B_ * L1_ * F1_;   // 1,112,064 floats per state buffer
    float* ws = (float*)d_ws;
    size_t ws_floats = ws_size / sizeof(float);
    float* x3 = ws;                  // (32,64,32)
    float* x4 = ws + 65536;          // (32,64,32)
    float *h1a, *h1b, *c1;
    if (ws_floats >= 131072 + 3*nH) {
        h1a = ws + 131072; h1b = h1a + nH; c1 = h1b + nH;
    } else {
        // fall back to scratch inside d_out (262 MB); consumed before head writes it
        h1a = (float*)d_out; h1b = h1a + nH; c1 = h1b + nH;
    }

    hipMemsetAsync(h1a, 0, nH*sizeof(float), stream);
    hipMemsetAsync(c1,  0, nH*sizeof(float), stream);

    float* cur = h1a; float* nxt = h1b;
    for (int t=0; t<T1_; ++t){
        lstm1_step<<<dim3(34, B_), 256, 0, stream>>>(x, Wx1, Wh1, b1, cur, nxt, c1, t);
        float* tmp = cur; cur = nxt; nxt = tmp;
    }
    lstm2_all<<<dim3(B_), 256, 0, stream>>>(cur, Wx2, Wh2, b2, x3);
    decoder_kernel<<<dim3(B_), 256, 0, stream>>>(x3, Wq,bq,Wk,bk,Wv,bv,Wo,bo,
                                                 g1,be1,W1,bf1,W2,bf2,g2,be2, x4);
    head_kernel<<<dim3(63, 128), 256, 0, stream>>>(x4, Wd, bd, (float*)d_out);
}

// Round 2
// 2904.986 us; speedup vs baseline: 3.4451x; 3.4451x over previous
//
#include <hip/hip_runtime.h>
#include <hip/hip_bf16.h>
#include <math.h>

#define B_  32
#define T1_ 128
#define L1_ 543
#define F1_ 64
#define T2_ 543
#define VOCAB_ 32000

typedef __attribute__((ext_vector_type(8))) short bf16x8;
typedef __attribute__((ext_vector_type(4))) float f32x4;

__device__ __forceinline__ short f2bf(float f){
    union { float f; unsigned u; } v; v.f = f;
    unsigned r = v.u + 0x7FFFu + ((v.u >> 16) & 1u);
    return (short)(r >> 16);
}
__device__ __forceinline__ float sigmoidf_(float x){ return 1.0f/(1.0f + expf(-x)); }

// ================= prepack Wh1/Wx1/b1 into MFMA B-fragment layout (bf16) =================
// Bp layout: frag (kt,nt) -> 64 lanes x 8 bf16. kt 0..5: Wh1 (K=192), kt 6: Wx1 im2col (9) + bias (k_local 9).
__global__ __launch_bounds__(256) void pack_B1(
    const float* __restrict__ Wh1,  // (3,64,256)
    const float* __restrict__ Wx1,  // (3,3,256)
    const float* __restrict__ b1,   // (256)
    short* __restrict__ Bp)         // 7*16*64*8 shorts
{
    int id = blockIdx.x*256 + threadIdx.x;
    if (id >= 7*16*64) return;
    int kt  = id >> 10;
    int rem = id & 1023;
    int nt  = rem >> 6;
    int lane= rem & 63;
    int j = nt*16 + (lane & 15);
    int g = lane >> 4;
    bf16x8 o;
    #pragma unroll
    for (int i=0;i<8;++i){
        int kl = 8*g + i;
        float v = 0.f;
        if (kt < 6){
            int tap = kt >> 1, ch = (kt & 1)*32 + kl;
            v = Wh1[(tap*64 + ch)*256 + j];
        } else {
            if (kl < 9){ int tap = kl/3, ch = kl - 3*tap; v = Wx1[(tap*3 + ch)*256 + j]; }
            else if (kl == 9) v = b1[j];
        }
        o[i] = f2bf(v);
    }
    *(bf16x8*)(Bp + (size_t)id*8) = o;
}

// ================= Stage 1: ConvLSTM1D #1, MFMA, one launch per timestep =================
// grid (9, 32), block 256 (4 waves). WG: l-chunk of 64 (M=64), N=256, K=192+ext.
// wave w handles N-tiles {w, 4+w, 8+w, 12+w} (gate q = tile index) x 4 M-tiles.
__global__ __launch_bounds__(256) void lstm1_step_mfma(
    const float* __restrict__ x,     // (B,128,543,3)
    const short* __restrict__ Bp,    // packed B frags
    const float* __restrict__ h_in,  // (B,543,64) fp32
    float* __restrict__ h_out,       // (B,543,64)
    float* __restrict__ cst,         // (B,543,64)
    int t)
{
    __shared__ short hs[66*72];      // bf16, row stride 72 (pad) -> 2-way banks
    __shared__ short xs[66*4];       // bf16 x rows l0-1..l0+64, 3ch+pad
    const int tid = threadIdx.x;
    const int w = tid >> 6, lane = tid & 63, g = lane >> 4, ln = lane & 15;
    const int b = blockIdx.y, l0 = blockIdx.x*64;

    // B fragments from packed buffer: 28 x b128 loads
    bf16x8 Bf[7][4];
    #pragma unroll
    for (int kt=0; kt<7; ++kt)
      #pragma unroll
      for (int q=0; q<4; ++q)
        Bf[kt][q] = *(const bf16x8*)(Bp + (size_t)(((kt*16 + (q*4 + w))*64) + lane)*8);

    // stage h chunk (66 rows x 64 ch) fp32 -> bf16 LDS
    const float* hb = h_in + (size_t)b*(L1_*64);
    for (int u = tid; u < 66*16; u += 256){
        int row = u >> 4, cq = u & 15;
        int l = l0 - 1 + row;
        float4 v = make_float4(0.f,0.f,0.f,0.f);
        if (l >= 0 && l < L1_) v = *(const float4*)(hb + (size_t)l*64 + cq*4);
        short4 s; s.x=f2bf(v.x); s.y=f2bf(v.y); s.z=f2bf(v.z); s.w=f2bf(v.w);
        *(short4*)(hs + row*72 + cq*4) = s;
    }
    // stage x rows (66 x 3)
    const float* xb = x + ((size_t)b*T1_ + t)*(L1_*3);
    for (int u = tid; u < 66*3; u += 256){
        int row = u/3, c = u - 3*row;
        int l = l0 - 1 + row;
        xs[row*4 + c] = f2bf((l>=0 && l<L1_) ? xb[l*3 + c] : 0.f);
    }
    __syncthreads();

    f32x4 zero4 = {0.f,0.f,0.f,0.f};
    f32x4 acc[4][4];
    #pragma unroll
    for (int mt=0; mt<4; ++mt)
      #pragma unroll
      for (int q=0; q<4; ++q) acc[mt][q] = zero4;

    #pragma unroll
    for (int mt=0; mt<4; ++mt){
        const int rbase = mt*16 + ln;
        #pragma unroll
        for (int kt=0; kt<6; ++kt){
            int tap = kt >> 1;
            bf16x8 a = *(const bf16x8*)(hs + (rbase + tap)*72 + (kt&1)*32 + 8*g);
            #pragma unroll
            for (int q=0;q<4;++q)
                acc[mt][q] = __builtin_amdgcn_mfma_f32_16x16x32_bf16(a, Bf[kt][q], acc[mt][q], 0,0,0);
        }
        // x + bias extension K-tile
        bf16x8 a6;
        #pragma unroll
        for (int i=0;i<8;++i) a6[i] = 0;
        if (g == 0){
            #pragma unroll
            for (int i=0;i<8;++i){ int tap = i/3, ch = i - 3*tap; a6[i] = xs[(rbase+tap)*4 + ch]; }
        } else if (g == 1){
            a6[0] = xs[(rbase+2)*4 + 2];       // k_local=8: tap 2, ch 2
            a6[1] = (short)0x3F80;             // k_local=9: bias multiplier 1.0
        }
        #pragma unroll
        for (int q=0;q<4;++q)
            acc[mt][q] = __builtin_amdgcn_mfma_f32_16x16x32_bf16(a6, Bf[6][q], acc[mt][q], 0,0,0);
    }

    // gates: lane owns channel c, rows l = l0 + mt*16 + 4g + r
    const int c = 16*w + ln;
    #pragma unroll
    for (int mt=0; mt<4; ++mt)
      #pragma unroll
      for (int r=0; r<4; ++r){
        int l = l0 + mt*16 + 4*g + r;
        if (l < L1_){
            size_t idx = ((size_t)b*L1_ + l)*64 + c;
            float cv = cst[idx];
            float iv = sigmoidf_(acc[mt][0][r]);
            float fv = sigmoidf_(acc[mt][1][r]);
            float gv = fmaxf(acc[mt][2][r], 0.f);
            float ov = sigmoidf_(acc[mt][3][r]);
            cv = fv*cv + iv*gv;
            cst[idx] = cv;
            h_out[idx] = ov * fmaxf(cv, 0.f);
        }
      }
}

// ================= Stage 2: ConvLSTM1D #2, MFMA, persistent 1 WG per batch =================
// M=64, N=128, K=96 (+x/bias ext). wave w = M-strip rows [16w,16w+16) x all 8 N-tiles.
__global__ __launch_bounds__(256) void lstm2_mfma(
    const float* __restrict__ x2,   // (B,543,64)
    const float* __restrict__ Wh2,  // (3,32,128)
    const float* __restrict__ Wx2,  // (3,1,128)
    const float* __restrict__ b2,   // (128)
    float* __restrict__ out)        // (B,64,32)
{
    __shared__ short hs[66*40];     // bf16 h, halo rows 0/65 zero, stride 40 (pad)
    __shared__ short xsb[66];       // bf16 x row, halo
    const int tid = threadIdx.x;
    const int w = tid>>6, lane = tid&63, g = lane>>4, ln = lane&15;
    const int b = blockIdx.x;

    // B-frags in registers for entire scan
    bf16x8 Bf[4][8];
    #pragma unroll
    for (int nt=0; nt<8; ++nt){
        int j = nt*16 + ln;
        #pragma unroll
        for (int kt=0; kt<3; ++kt){
            bf16x8 o;
            #pragma unroll
            for (int i=0;i<8;++i) o[i] = f2bf(Wh2[(kt*32 + 8*g + i)*128 + j]);
            Bf[kt][nt] = o;
        }
        bf16x8 o;
        #pragma unroll
        for (int i=0;i<8;++i) o[i] = 0;
        if (g==0){
            o[0]=f2bf(Wx2[0*128+j]); o[1]=f2bf(Wx2[1*128+j]); o[2]=f2bf(Wx2[2*128+j]);
            o[3]=f2bf(b2[j]);
        }
        Bf[3][nt] = o;
    }

    for (int i=tid; i<66*40; i+=256) hs[i]=0;
    if (tid<66) xsb[tid]=0;
    float creg[8];
    #pragma unroll
    for (int i=0;i<8;++i) creg[i]=0.f;
    __syncthreads();

    const float* xb = x2 + (size_t)b*(T2_*64);
    const int lA = 16*w + ln;       // A-operand row for this lane

    for (int t=0; t<T2_; ++t){
        if (tid < 64) xsb[1+tid] = f2bf(xb[(size_t)t*64 + tid]);
        __syncthreads();            // h(t-1) writes + x row visible

        f32x4 acc[8];
        f32x4 zero4 = {0.f,0.f,0.f,0.f};
        #pragma unroll
        for (int nt=0; nt<8; ++nt) acc[nt] = zero4;

        #pragma unroll
        for (int kt=0; kt<3; ++kt){
            bf16x8 a = *(const bf16x8*)(hs + (lA + kt)*40 + 8*g);
            #pragma unroll
            for (int nt=0; nt<8; ++nt)
                acc[nt] = __builtin_amdgcn_mfma_f32_16x16x32_bf16(a, Bf[kt][nt], acc[nt], 0,0,0);
        }
        {
            bf16x8 a3;
            #pragma unroll
            for (int i=0;i<8;++i) a3[i] = 0;
            if (g==0){
                a3[0]=xsb[lA]; a3[1]=xsb[lA+1]; a3[2]=xsb[lA+2];
                a3[3]=(short)0x3F80;
            }
            #pragma unroll
            for (int nt=0; nt<8; ++nt)
                acc[nt] = __builtin_amdgcn_mfma_f32_16x16x32_bf16(a3, Bf[3][nt], acc[nt], 0,0,0);
        }
        __syncthreads();            // all A-reads done before h overwrite

        #pragma unroll
        for (int cc=0; cc<2; ++cc)
          #pragma unroll
          for (int r=0; r<4; ++r){
            int l = 16*w + 4*g + r;
            int ch = ln + 16*cc;
            float cv = creg[cc*4+r];
            float iv = sigmoidf_(acc[0+cc][r]);
            float fv = sigmoidf_(acc[2+cc][r]);
            float gv = fmaxf(acc[4+cc][r], 0.f);
            float ov = sigmoidf_(acc[6+cc][r]);
            cv = fv*cv + iv*gv;
            creg[cc*4+r] = cv;
            float hv = ov * fmaxf(cv, 0.f);
            hs[(1+l)*40 + ch] = f2bf(hv);
            if (t == T2_-1) out[(size_t)b*2048 + l*32 + ch] = hv;
          }
    }
}

// ================= Transformer decoder, 1 WG per batch (unchanged) =================
__global__ __launch_bounds__(256) void decoder_kernel(
    const float* __restrict__ xin,
    const float* __restrict__ Wq, const float* __restrict__ bq,
    const float* __restrict__ Wk, const float* __restrict__ bk,
    const float* __restrict__ Wv, const float* __restrict__ bv,
    const float* __restrict__ Wo, const float* __restrict__ bo,
    const float* __restrict__ g1, const float* __restrict__ be1,
    const float* __restrict__ W1, const float* __restrict__ bf1,
    const float* __restrict__ W2, const float* __restrict__ bf2,
    const float* __restrict__ g2, const float* __restrict__ be2,
    float* __restrict__ xout)
{
    __shared__ float smem[16384];
    float* sx  = smem;
    float* sq  = smem + 2048;
    float* sk  = smem + 4096;
    float* sv  = smem + 6144;
    float* so  = smem + 8192;
    float* sy  = smem + 10240;
    float* sff = smem + 12288;

    const int b = blockIdx.x;
    const int tid = threadIdx.x;

    for (int i=tid; i<2048; i+=256) sx[i] = xin[(size_t)b*2048 + i];
    __syncthreads();

    for (int i=tid; i<2048; i+=256){
        int s = i >> 5, j = i & 31;
        float aq = bq[j], ak = bk[j], av = bv[j];
        for (int d=0; d<32; ++d){
            float xv = sx[s*32+d];
            aq = fmaf(xv, Wq[d*32+j], aq);
            ak = fmaf(xv, Wk[d*32+j], ak);
            av = fmaf(xv, Wv[d*32+j], av);
        }
        sq[i]=aq; sk[i]=ak; sv[i]=av;
    }
    __syncthreads();

    if (tid < 128){
        int h = tid >> 6, si = tid & 63;
        const int o = h*16;
        float qv[16];
        #pragma unroll
        for (int kk=0; kk<16; ++kk) qv[kk] = sq[si*32 + o + kk];
        float mx = -1e30f;
        for (int ti=0; ti<=si; ++ti){
            float sc = 0.f;
            #pragma unroll
            for (int kk=0; kk<16; ++kk) sc = fmaf(qv[kk], sk[ti*32+o+kk], sc);
            mx = fmaxf(mx, sc*0.25f);
        }
        float sum = 0.f;
        float accv[16];
        #pragma unroll
        for (int kk=0; kk<16; ++kk) accv[kk]=0.f;
        for (int ti=0; ti<=si; ++ti){
            float sc = 0.f;
            #pragma unroll
            for (int kk=0; kk<16; ++kk) sc = fmaf(qv[kk], sk[ti*32+o+kk], sc);
            float p = expf(sc*0.25f - mx);
            sum += p;
            #pragma unroll
            for (int kk=0; kk<16; ++kk) accv[kk] = fmaf(p, sv[ti*32+o+kk], accv[kk]);
        }
        float inv = 1.f/sum;
        #pragma unroll
        for (int kk=0; kk<16; ++kk) so[si*32 + o + kk] = accv[kk]*inv;
    }
    __syncthreads();

    for (int i=tid; i<2048; i+=256){
        int s = i>>5, d = i&31;
        float a = bo[d];
        for (int j=0; j<32; ++j) a = fmaf(so[s*32+j], Wo[j*32+d], a);
        sy[i] = sx[i] + a;
    }
    __syncthreads();
    if (tid < 64){
        float mu=0.f;
        for (int d=0; d<32; ++d) mu += sy[tid*32+d];
        mu *= (1.f/32.f);
        float var=0.f;
        for (int d=0; d<32; ++d){ float dd = sy[tid*32+d]-mu; var = fmaf(dd,dd,var); }
        var *= (1.f/32.f);
        float rs = rsqrtf(var + 1e-5f);
        for (int d=0; d<32; ++d) sy[tid*32+d] = (sy[tid*32+d]-mu)*rs*g1[d] + be1[d];
    }
    __syncthreads();
    for (int i=tid; i<4096; i+=256){
        int s = i>>6, ff = i&63;
        float a = bf1[ff];
        for (int d=0; d<32; ++d) a = fmaf(sy[s*32+d], W1[d*64+ff], a);
        sff[i] = fmaxf(a, 0.f);
    }
    __syncthreads();
    for (int i=tid; i<2048; i+=256){
        int s=i>>5, d=i&31;
        float a = bf2[d];
        for (int ff=0; ff<64; ++ff) a = fmaf(sff[s*64+ff], W2[ff*32+d], a);
        sx[i] = sy[i] + a;
    }
    __syncthreads();
    if (tid < 64){
        float mu=0.f;
        for (int d=0; d<32; ++d) mu += sx[tid*32+d];
        mu *= (1.f/32.f);
        float var=0.f;
        for (int d=0; d<32; ++d){ float dd = sx[tid*32+d]-mu; var = fmaf(dd,dd,var); }
        var *= (1.f/32.f);
        float rs = rsqrtf(var + 1e-5f);
        for (int d=0; d<32; ++d)
            xout[(size_t)b*2048 + tid*32 + d] = (sx[tid*32+d]-mu)*rs*g2[d] + be2[d];
    }
}

// ================= Vocab head (unchanged) =================
__global__ __launch_bounds__(256) void head_kernel(
    const float* __restrict__ xin,
    const float* __restrict__ Wd,
    const float* __restrict__ bd,
    float* __restrict__ out)
{
    __shared__ float sxr[16*32];
    const int r0 = blockIdx.y * 16;
    const int c0 = blockIdx.x * 512;
    const int tid = threadIdx.x;
    for (int i=tid; i<512; i+=256) sxr[i] = xin[(size_t)(r0 + (i>>5))*32 + (i&31)];
    __syncthreads();
    int c = c0 + tid*2;
    if (c >= VOCAB_) return;
    float a0[16], a1[16];
    float b0 = bd[c], b1 = bd[c+1];
    #pragma unroll
    for (int r=0; r<16; ++r){ a0[r]=b0; a1[r]=b1; }
    for (int d=0; d<32; ++d){
        float w0 = Wd[(size_t)d*VOCAB_ + c];
        float w1 = Wd[(size_t)d*VOCAB_ + c + 1];
        #pragma unroll
        for (int r=0; r<16; ++r){
            float xv = sxr[r*32+d];
            a0[r] = fmaf(xv, w0, a0[r]);
            a1[r] = fmaf(xv, w1, a1[r]);
        }
    }
    #pragma unroll
    for (int r=0; r<16; ++r){
        float2 v = make_float2(a0[r], a1[r]);
        *reinterpret_cast<float2*>(&out[(size_t)(r0+r)*VOCAB_ + c]) = v;
    }
}

// ================= launch =================
extern "C" void kernel_launch(void* const* d_in, const int* in_sizes, int n_in,
                              void* d_out, int out_size, void* d_ws, size_t ws_size,
                              hipStream_t stream)
{
    const float* x   = (const float*)d_in[0];
    const float* Wx1 = (const float*)d_in[1];
    const float* Wh1 = (const float*)d_in[2];
    const float* b1  = (const float*)d_in[3];
    const float* Wx2 = (const float*)d_in[4];
    const float* Wh2 = (const float*)d_in[5];
    const float* b2  = (const float*)d_in[6];
    const float* Wq  = (const float*)d_in[7];
    const float* bq  = (const float*)d_in[8];
    const float* Wk  = (const float*)d_in[9];
    const float* bk  = (const float*)d_in[10];
    const float* Wv  = (const float*)d_in[11];
    const float* bv  = (const float*)d_in[12];
    const float* Wo  = (const float*)d_in[13];
    const float* bo  = (const float*)d_in[14];
    const float* g1  = (const float*)d_in[15];
    const float* be1 = (const float*)d_in[16];
    const float* W1  = (const float*)d_in[17];
    const float* bf1 = (const float*)d_in[18];
    const float* W2  = (const float*)d_in[19];
    const float* bf2 = (const float*)d_in[20];
    const float* g2  = (const float*)d_in[21];
    const float* be2 = (const float*)d_in[22];
    const float* Wd  = (const float*)d_in[23];
    const float* bd  = (const float*)d_in[24];

    const size_t nH = (size_t)B_ * L1_ * 64;    // 1,112,064 floats
    float* ws = (float*)d_ws;
    size_t ws_floats = ws_size / sizeof(float);
    float* x3 = ws;                          // 65536 floats
    float* x4 = ws + 65536;                  // 65536 floats
    short* Bp = (short*)(ws + 131072);       // 57344 shorts = 28672 floats
    float* hbase = ws + 131072 + 28672;
    float *h1a, *h1b, *c1;
    if (ws_floats >= 131072 + 28672 + 3*nH) {
        h1a = hbase; h1b = h1a + nH; c1 = h1b + nH;
    } else {
        // scratch inside d_out (262 MB); fully consumed before head writes it
        h1a = (float*)d_out; h1b = h1a + nH; c1 = h1b + nH;
    }

    hipMemsetAsync(h1a, 0, nH*sizeof(float), stream);
    hipMemsetAsync(c1,  0, nH*sizeof(float), stream);

    pack_B1<<<28, 256, 0, stream>>>(Wh1, Wx1, b1, Bp);

    float* cur = h1a; float* nxt = h1b;
    for (int t=0; t<T1_; ++t){
        lstm1_step_mfma<<<dim3(9, B_), 256, 0, stream>>>(x, Bp, cur, nxt, c1, t);
        float* tmp = cur; cur = nxt; nxt = tmp;
    }
    lstm2_mfma<<<dim3(B_), 256, 0, stream>>>(cur, Wh2, Wx2, b2, x3);
    decoder_kernel<<<dim3(B_), 256, 0, stream>>>(x3, Wq,bq,Wk,bk,Wv,bv,Wo,bo,
                                                 g1,be1,W1,bf1,W2,bf2,g2,be2, x4);
    head_kernel<<<dim3(63, 128), 256, 0, stream>>>(x4, Wd, bd, (float*)d_out);
}

// Round 3
// 1997.325 us; speedup vs baseline: 5.0106x; 1.4544x over previous
//
#include <hip/hip_runtime.h>
#include <hip/hip_bf16.h>
#include <math.h>

#define B_  32
#define T1_ 128
#define L1_ 543
#define T2_ 543
#define VOCAB_ 32000

typedef __attribute__((ext_vector_type(8))) short bf16x8;
typedef __attribute__((ext_vector_type(4))) float f32x4;
typedef unsigned short ushort_t;

__device__ __forceinline__ short f2bf(float f){
    union { float f; unsigned u; } v; v.f = f;
    unsigned r = v.u + 0x7FFFu + ((v.u >> 16) & 1u);
    return (short)(r >> 16);
}
__device__ __forceinline__ float frcp_(float x){
    float r; asm("v_rcp_f32 %0, %1" : "=v"(r) : "v"(x));
    return r * (2.0f - x*r);   // one Newton step
}
__device__ __forceinline__ float fsig(float x){ return frcp_(1.0f + __expf(-x)); }

// ================= prepack Wh1/Wx1/b1 into MFMA B-fragment layout (bf16) =================
__global__ __launch_bounds__(256) void pack_B1(
    const float* __restrict__ Wh1,  // (3,64,256)
    const float* __restrict__ Wx1,  // (3,3,256)
    const float* __restrict__ b1,   // (256)
    short* __restrict__ Bp)         // 7*16*64*8 shorts
{
    int id = blockIdx.x*256 + threadIdx.x;
    if (id >= 7*16*64) return;
    int kt  = id >> 10;
    int rem = id & 1023;
    int nt  = rem >> 6;
    int lane= rem & 63;
    int j = nt*16 + (lane & 15);
    int g = lane >> 4;
    bf16x8 o;
    #pragma unroll
    for (int i=0;i<8;++i){
        int kl = 8*g + i;
        float v = 0.f;
        if (kt < 6){
            int tap = kt >> 1, ch = (kt & 1)*32 + kl;
            v = Wh1[(tap*64 + ch)*256 + j];
        } else {
            if (kl < 9){ int tap = kl/3, ch = kl - 3*tap; v = Wx1[(tap*3 + ch)*256 + j]; }
            else if (kl == 9) v = b1[j];
        }
        o[i] = f2bf(v);
    }
    *(bf16x8*)(Bp + (size_t)id*8) = o;
}

// ================= Stage 1: ConvLSTM1D #1, MFMA, TWO timesteps per launch =================
// grid (9, 32), block 256 (4 waves). Chunk = 64 interior rows.
// Step A: h(t) for rows l0-1..l0+64 (66 rows, 5 M-tiles) -> LDS. Step B: h(t+1)/c(t+1) interior.
__global__ __launch_bounds__(256) void lstm1_step2_mfma(
    const float* __restrict__ x,       // (B,128,543,3) fp32
    const short* __restrict__ Bp,      // packed B frags
    const ushort_t* __restrict__ h_in, // (B,543,64) bf16 = h(t-1)
    ushort_t* __restrict__ h_out,      // (B,543,64) bf16 = h(t+1)
    const float* __restrict__ c_in,    // (B,543,64) fp32 = c(t-1)
    float* __restrict__ c_out,         // (B,543,64) fp32 = c(t+1)
    int t)
{
    __shared__ short hA[82*72];        // h(t-1), rows <-> l0-2+r  (rows 66..81 staged too, feed discarded tiles)
    __shared__ short hB[66*72];        // h(t),   rows <-> l0-1+r
    __shared__ short xA[82*4];         // x(t),   rows <-> l0-2+r
    __shared__ short xB[66*4];         // x(t+1), rows <-> l0-1+r
    __shared__ float cL[66*68];        // c(t),   rows <-> l0-1+r
    const int tid = threadIdx.x;
    const int w = tid>>6, lane = tid&63, g = lane>>4, ln = lane&15;
    const int b = blockIdx.y, l0 = blockIdx.x*64;
    const int ch = 16*w + ln;

    // early c(t-1) loads (used only in gate phase A; latency hidden under staging + MFMA A)
    float cr[5][4];
    #pragma unroll
    for (int mt=0; mt<5; ++mt)
      #pragma unroll
      for (int r=0; r<4; ++r){
        int mA = mt*16 + 4*g + r;
        int l = l0 - 1 + mA;
        cr[mt][r] = (mA < 66 && l >= 0 && l < L1_) ? c_in[((size_t)b*L1_ + l)*64 + ch] : 0.f;
      }

    // B fragments (shared by both steps): 28 x b128 loads
    bf16x8 Bf[7][4];
    #pragma unroll
    for (int kt=0; kt<7; ++kt)
      #pragma unroll
      for (int q=0; q<4; ++q)
        Bf[kt][q] = *(const bf16x8*)(Bp + (size_t)(((kt*16 + (q*4 + w))*64) + lane)*8);

    // stage h(t-1): 82 rows x 64 ch bf16 (16B vector copies)
    const ushort_t* hb = h_in + (size_t)b*(L1_*64);
    for (int u=tid; u<82*8; u+=256){
        int row = u>>3, cq = u&7;
        int l = l0 - 2 + row;
        uint4 v = make_uint4(0u,0u,0u,0u);
        if (l >= 0 && l < L1_) v = *(const uint4*)(hb + (size_t)l*64 + cq*8);
        *(uint4*)(hA + row*72 + cq*8) = v;
    }
    // stage x(t) 82 rows, x(t+1) 66 rows
    const float* xt = x + ((size_t)b*T1_ + t)*(L1_*3);
    for (int u=tid; u<82*3; u+=256){
        int row = u/3, c = u - 3*row;
        int l = l0 - 2 + row;
        xA[row*4+c] = f2bf((l>=0 && l<L1_) ? xt[l*3+c] : 0.f);
    }
    for (int u=tid; u<66*3; u+=256){
        int row = u/3, c = u - 3*row;
        int l = l0 - 1 + row;
        xB[row*4+c] = f2bf((l>=0 && l<L1_) ? xt[L1_*3 + l*3+c] : 0.f);
    }
    __syncthreads();

    // ---- step A: z(t) for 5 M-tiles (rows l0-1 .. l0+64 valid, rest discarded) ----
    f32x4 zero4 = {0.f,0.f,0.f,0.f};
    {
        f32x4 acc[5][4];
        #pragma unroll
        for (int mt=0; mt<5; ++mt)
          #pragma unroll
          for (int q=0; q<4; ++q) acc[mt][q] = zero4;

        #pragma unroll
        for (int mt=0; mt<5; ++mt){
            const int rbase = mt*16 + ln;
            #pragma unroll
            for (int kt=0; kt<6; ++kt){
                int tap = kt >> 1;
                bf16x8 a = *(const bf16x8*)(hA + (rbase + tap)*72 + (kt&1)*32 + 8*g);
                #pragma unroll
                for (int q=0;q<4;++q)
                    acc[mt][q] = __builtin_amdgcn_mfma_f32_16x16x32_bf16(a, Bf[kt][q], acc[mt][q], 0,0,0);
            }
            bf16x8 a6;
            #pragma unroll
            for (int i=0;i<8;++i) a6[i] = 0;
            if (g == 0){
                #pragma unroll
                for (int i=0;i<8;++i){ int tap = i/3, c = i - 3*tap; a6[i] = xA[(rbase+tap)*4 + c]; }
            } else if (g == 1){
                a6[0] = xA[(rbase+2)*4 + 2];
                a6[1] = (short)0x3F80;
            }
            #pragma unroll
            for (int q=0;q<4;++q)
                acc[mt][q] = __builtin_amdgcn_mfma_f32_16x16x32_bf16(a6, Bf[6][q], acc[mt][q], 0,0,0);
        }

        // gate phase A: h(t) -> hB (bf16), c(t) -> cL (fp32)
        #pragma unroll
        for (int mt=0; mt<5; ++mt)
          #pragma unroll
          for (int r=0; r<4; ++r){
            int mA = mt*16 + 4*g + r;
            if (mA < 66){
                int l = l0 - 1 + mA;
                float cv = 0.f, hv = 0.f;
                if (l >= 0 && l < L1_){
                    float iv = fsig(acc[mt][0][r]);
                    float fv = fsig(acc[mt][1][r]);
                    float gv = fmaxf(acc[mt][2][r], 0.f);
                    float ov = fsig(acc[mt][3][r]);
                    cv = fv*cr[mt][r] + iv*gv;
                    hv = ov * fmaxf(cv, 0.f);
                }
                cL[mA*68 + ch] = cv;
                hB[mA*72 + ch] = f2bf(hv);
            }
          }
    }
    __syncthreads();

    // ---- step B: z(t+1) for 4 interior M-tiles ----
    {
        f32x4 acc[4][4];
        #pragma unroll
        for (int mt=0; mt<4; ++mt)
          #pragma unroll
          for (int q=0; q<4; ++q) acc[mt][q] = zero4;

        #pragma unroll
        for (int mt=0; mt<4; ++mt){
            const int rbase = mt*16 + ln;
            #pragma unroll
            for (int kt=0; kt<6; ++kt){
                int tap = kt >> 1;
                bf16x8 a = *(const bf16x8*)(hB + (rbase + tap)*72 + (kt&1)*32 + 8*g);
                #pragma unroll
                for (int q=0;q<4;++q)
                    acc[mt][q] = __builtin_amdgcn_mfma_f32_16x16x32_bf16(a, Bf[kt][q], acc[mt][q], 0,0,0);
            }
            bf16x8 a6;
            #pragma unroll
            for (int i=0;i<8;++i) a6[i] = 0;
            if (g == 0){
                #pragma unroll
                for (int i=0;i<8;++i){ int tap = i/3, c = i - 3*tap; a6[i] = xB[(rbase+tap)*4 + c]; }
            } else if (g == 1){
                a6[0] = xB[(rbase+2)*4 + 2];
                a6[1] = (short)0x3F80;
            }
            #pragma unroll
            for (int q=0;q<4;++q)
                acc[mt][q] = __builtin_amdgcn_mfma_f32_16x16x32_bf16(a6, Bf[6][q], acc[mt][q], 0,0,0);
        }

        // gate phase B: write h(t+1) bf16 + c(t+1) fp32 to global (interior only)
        #pragma unroll
        for (int mt=0; mt<4; ++mt)
          #pragma unroll
          for (int r=0; r<4; ++r){
            int mB = mt*16 + 4*g + r;
            int l = l0 + mB;
            if (l < L1_){
                float ct = cL[(mB+1)*68 + ch];
                float iv = fsig(acc[mt][0][r]);
                float fv = fsig(acc[mt][1][r]);
                float gv = fmaxf(acc[mt][2][r], 0.f);
                float ov = fsig(acc[mt][3][r]);
                float cv = fv*ct + iv*gv;
                float hv = ov * fmaxf(cv, 0.f);
                size_t idx = ((size_t)b*L1_ + l)*64 + ch;
                c_out[idx] = cv;
                h_out[idx] = (ushort_t)f2bf(hv);
            }
          }
    }
}

// ================= Stage 2: ConvLSTM1D #2, MFMA, persistent 1 WG per batch =================
__global__ __launch_bounds__(256) void lstm2_mfma(
    const ushort_t* __restrict__ x2, // (B,543,64) bf16
    const float* __restrict__ Wh2,   // (3,32,128)
    const float* __restrict__ Wx2,   // (3,1,128)
    const float* __restrict__ b2,    // (128)
    float* __restrict__ out)         // (B,64,32)
{
    __shared__ short hs[66*40];
    __shared__ short xsb[66];
    const int tid = threadIdx.x;
    const int w = tid>>6, lane = tid&63, g = lane>>4, ln = lane&15;
    const int b = blockIdx.x;

    bf16x8 Bf[4][8];
    #pragma unroll
    for (int nt=0; nt<8; ++nt){
        int j = nt*16 + ln;
        #pragma unroll
        for (int kt=0; kt<3; ++kt){
            bf16x8 o;
            #pragma unroll
            for (int i=0;i<8;++i) o[i] = f2bf(Wh2[(kt*32 + 8*g + i)*128 + j]);
            Bf[kt][nt] = o;
        }
        bf16x8 o;
        #pragma unroll
        for (int i=0;i<8;++i) o[i] = 0;
        if (g==0){
            o[0]=f2bf(Wx2[0*128+j]); o[1]=f2bf(Wx2[1*128+j]); o[2]=f2bf(Wx2[2*128+j]);
            o[3]=f2bf(b2[j]);
        }
        Bf[3][nt] = o;
    }

    for (int i=tid; i<66*40; i+=256) hs[i]=0;
    if (tid<66) xsb[tid]=0;
    float creg[8];
    #pragma unroll
    for (int i=0;i<8;++i) creg[i]=0.f;

    const ushort_t* xb = x2 + (size_t)b*(T2_*64);
    ushort_t xreg = (tid < 64) ? xb[tid] : (ushort_t)0;   // prefetch t=0
    __syncthreads();

    const int lA = 16*w + ln;

    for (int t=0; t<T2_; ++t){
        if (tid < 64) xsb[1+tid] = (short)xreg;
        __syncthreads();            // h(t-1) writes + x row visible
        if (tid < 64 && t+1 < T2_) xreg = xb[(size_t)(t+1)*64 + tid];  // prefetch next (hidden)

        f32x4 acc[8];
        f32x4 zero4 = {0.f,0.f,0.f,0.f};
        #pragma unroll
        for (int nt=0; nt<8; ++nt) acc[nt] = zero4;

        #pragma unroll
        for (int kt=0; kt<3; ++kt){
            bf16x8 a = *(const bf16x8*)(hs + (lA + kt)*40 + 8*g);
            #pragma unroll
            for (int nt=0; nt<8; ++nt)
                acc[nt] = __builtin_amdgcn_mfma_f32_16x16x32_bf16(a, Bf[kt][nt], acc[nt], 0,0,0);
        }
        {
            bf16x8 a3;
            #pragma unroll
            for (int i=0;i<8;++i) a3[i] = 0;
            if (g==0){
                a3[0]=xsb[lA]; a3[1]=xsb[lA+1]; a3[2]=xsb[lA+2];
                a3[3]=(short)0x3F80;
            }
            #pragma unroll
            for (int nt=0; nt<8; ++nt)
                acc[nt] = __builtin_amdgcn_mfma_f32_16x16x32_bf16(a3, Bf[3][nt], acc[nt], 0,0,0);
        }
        __syncthreads();            // all A-reads done before h overwrite

        #pragma unroll
        for (int cc=0; cc<2; ++cc)
          #pragma unroll
          for (int r=0; r<4; ++r){
            int l = 16*w + 4*g + r;
            int chn = ln + 16*cc;
            float cv = creg[cc*4+r];
            float iv = fsig(acc[0+cc][r]);
            float fv = fsig(acc[2+cc][r]);
            float gv = fmaxf(acc[4+cc][r], 0.f);
            float ov = fsig(acc[6+cc][r]);
            cv = fv*cv + iv*gv;
            creg[cc*4+r] = cv;
            float hv = ov * fmaxf(cv, 0.f);
            hs[(1+l)*40 + chn] = f2bf(hv);
            if (t == T2_-1) out[(size_t)b*2048 + l*32 + chn] = hv;
          }
    }
}

// ================= Transformer decoder, 1 WG per batch =================
__global__ __launch_bounds__(256) void decoder_kernel(
    const float* __restrict__ xin,
    const float* __restrict__ Wq, const float* __restrict__ bq,
    const float* __restrict__ Wk, const float* __restrict__ bk,
    const float* __restrict__ Wv, const float* __restrict__ bv,
    const float* __restrict__ Wo, const float* __restrict__ bo,
    const float* __restrict__ g1, const float* __restrict__ be1,
    const float* __restrict__ W1, const float* __restrict__ bf1,
    const float* __restrict__ W2, const float* __restrict__ bf2,
    const float* __restrict__ g2, const float* __restrict__ be2,
    float* __restrict__ xout)
{
    __shared__ float smem[16384];
    float* sx  = smem;
    float* sq  = smem + 2048;
    float* sk  = smem + 4096;
    float* sv  = smem + 6144;
    float* so  = smem + 8192;
    float* sy  = smem + 10240;
    float* sff = smem + 12288;

    const int b = blockIdx.x;
    const int tid = threadIdx.x;

    for (int i=tid; i<2048; i+=256) sx[i] = xin[(size_t)b*2048 + i];
    __syncthreads();

    for (int i=tid; i<2048; i+=256){
        int s = i >> 5, j = i & 31;
        float aq = bq[j], ak = bk[j], av = bv[j];
        for (int d=0; d<32; ++d){
            float xv = sx[s*32+d];
            aq = fmaf(xv, Wq[d*32+j], aq);
            ak = fmaf(xv, Wk[d*32+j], ak);
            av = fmaf(xv, Wv[d*32+j], av);
        }
        sq[i]=aq; sk[i]=ak; sv[i]=av;
    }
    __syncthreads();

    if (tid < 128){
        int h = tid >> 6, si = tid & 63;
        const int o = h*16;
        float qv[16];
        #pragma unroll
        for (int kk=0; kk<16; ++kk) qv[kk] = sq[si*32 + o + kk];
        float mx = -1e30f;
        for (int ti=0; ti<=si; ++ti){
            float sc = 0.f;
            #pragma unroll
            for (int kk=0; kk<16; ++kk) sc = fmaf(qv[kk], sk[ti*32+o+kk], sc);
            mx = fmaxf(mx, sc*0.25f);
        }
        float sum = 0.f;
        float accv[16];
        #pragma unroll
        for (int kk=0; kk<16; ++kk) accv[kk]=0.f;
        for (int ti=0; ti<=si; ++ti){
            float sc = 0.f;
            #pragma unroll
            for (int kk=0; kk<16; ++kk) sc = fmaf(qv[kk], sk[ti*32+o+kk], sc);
            float p = expf(sc*0.25f - mx);
            sum += p;
            #pragma unroll
            for (int kk=0; kk<16; ++kk) accv[kk] = fmaf(p, sv[ti*32+o+kk], accv[kk]);
        }
        float inv = 1.f/sum;
        #pragma unroll
        for (int kk=0; kk<16; ++kk) so[si*32 + o + kk] = accv[kk]*inv;
    }
    __syncthreads();

    for (int i=tid; i<2048; i+=256){
        int s = i>>5, d = i&31;
        float a = bo[d];
        for (int j=0; j<32; ++j) a = fmaf(so[s*32+j], Wo[j*32+d], a);
        sy[i] = sx[i] + a;
    }
    __syncthreads();
    if (tid < 64){
        float mu=0.f;
        for (int d=0; d<32; ++d) mu += sy[tid*32+d];
        mu *= (1.f/32.f);
        float var=0.f;
        for (int d=0; d<32; ++d){ float dd = sy[tid*32+d]-mu; var = fmaf(dd,dd,var); }
        var *= (1.f/32.f);
        float rs = rsqrtf(var + 1e-5f);
        for (int d=0; d<32; ++d) sy[tid*32+d] = (sy[tid*32+d]-mu)*rs*g1[d] + be1[d];
    }
    __syncthreads();
    for (int i=tid; i<4096; i+=256){
        int s = i>>6, ff = i&63;
        float a = bf1[ff];
        for (int d=0; d<32; ++d) a = fmaf(sy[s*32+d], W1[d*64+ff], a);
        sff[i] = fmaxf(a, 0.f);
    }
    __syncthreads();
    for (int i=tid; i<2048; i+=256){
        int s=i>>5, d=i&31;
        float a = bf2[d];
        for (int ff=0; ff<64; ++ff) a = fmaf(sff[s*64+ff], W2[ff*32+d], a);
        sx[i] = sy[i] + a;
    }
    __syncthreads();
    if (tid < 64){
        float mu=0.f;
        for (int d=0; d<32; ++d) mu += sx[tid*32+d];
        mu *= (1.f/32.f);
        float var=0.f;
        for (int d=0; d<32; ++d){ float dd = sx[tid*32+d]-mu; var = fmaf(dd,dd,var); }
        var *= (1.f/32.f);
        float rs = rsqrtf(var + 1e-5f);
        for (int d=0; d<32; ++d)
            xout[(size_t)b*2048 + tid*32 + d] = (sx[tid*32+d]-mu)*rs*g2[d] + be2[d];
    }
}

// ================= Vocab head =================
__global__ __launch_bounds__(256) void head_kernel(
    const float* __restrict__ xin,
    const float* __restrict__ Wd,
    const float* __restrict__ bd,
    float* __restrict__ out)
{
    __shared__ float sxr[16*32];
    const int r0 = blockIdx.y * 16;
    const int c0 = blockIdx.x * 512;
    const int tid = threadIdx.x;
    for (int i=tid; i<512; i+=256) sxr[i] = xin[(size_t)(r0 + (i>>5))*32 + (i&31)];
    __syncthreads();
    int c = c0 + tid*2;
    if (c >= VOCAB_) return;
    float a0[16], a1[16];
    float b0 = bd[c], b1 = bd[c+1];
    #pragma unroll
    for (int r=0; r<16; ++r){ a0[r]=b0; a1[r]=b1; }
    for (int d=0; d<32; ++d){
        float w0 = Wd[(size_t)d*VOCAB_ + c];
        float w1 = Wd[(size_t)d*VOCAB_ + c + 1];
        #pragma unroll
        for (int r=0; r<16; ++r){
            float xv = sxr[r*32+d];
            a0[r] = fmaf(xv, w0, a0[r]);
            a1[r] = fmaf(xv, w1, a1[r]);
        }
    }
    #pragma unroll
    for (int r=0; r<16; ++r){
        float2 v = make_float2(a0[r], a1[r]);
        *reinterpret_cast<float2*>(&out[(size_t)(r0+r)*VOCAB_ + c]) = v;
    }
}

// ================= launch =================
extern "C" void kernel_launch(void* const* d_in, const int* in_sizes, int n_in,
                              void* d_out, int out_size, void* d_ws, size_t ws_size,
                              hipStream_t stream)
{
    const float* x   = (const float*)d_in[0];
    const float* Wx1 = (const float*)d_in[1];
    const float* Wh1 = (const float*)d_in[2];
    const float* b1  = (const float*)d_in[3];
    const float* Wx2 = (const float*)d_in[4];
    const float* Wh2 = (const float*)d_in[5];
    const float* b2  = (const float*)d_in[6];
    const float* Wq  = (const float*)d_in[7];
    const float* bq  = (const float*)d_in[8];
    const float* Wk  = (const float*)d_in[9];
    const float* bk  = (const float*)d_in[10];
    const float* Wv  = (const float*)d_in[11];
    const float* bv  = (const float*)d_in[12];
    const float* Wo  = (const float*)d_in[13];
    const float* bo  = (const float*)d_in[14];
    const float* g1  = (const float*)d_in[15];
    const float* be1 = (const float*)d_in[16];
    const float* W1  = (const float*)d_in[17];
    const float* bf1 = (const float*)d_in[18];
    const float* W2  = (const float*)d_in[19];
    const float* bf2 = (const float*)d_in[20];
    const float* g2  = (const float*)d_in[21];
    const float* be2 = (const float*)d_in[22];
    const float* Wd  = (const float*)d_in[23];
    const float* bd  = (const float*)d_in[24];

    const size_t nH = (size_t)B_ * L1_ * 64;    // 1,112,064 elements per state buffer
    float* ws = (float*)d_ws;
    size_t ws_floats = ws_size / sizeof(float);
    float* x3 = ws;                          // 65536 floats
    float* x4 = ws + 65536;                  // 65536 floats
    short* Bp = (short*)(ws + 131072);       // 57344 shorts = 28672 floats
    // state: h double-buffer (bf16), c double-buffer (fp32)
    const size_t base_f = 131072 + 28672;                  // float offset
    const size_t need_f = base_f + nH/2*2 /*2 bf16 bufs*/ + 2*nH /*2 f32 bufs*/;
    float* statebase;
    if (ws_floats >= need_f) statebase = ws + base_f;
    else                     statebase = (float*)d_out;    // 262MB scratch, consumed before head writes
    ushort_t* h1a = (ushort_t*)statebase;                  // nH bf16
    ushort_t* h1b = h1a + nH;                              // nH bf16
    float*    c1a = (float*)(h1b + nH);                    // nH f32
    float*    c1b = c1a + nH;                              // nH f32

    hipMemsetAsync(h1a, 0, nH*sizeof(ushort_t), stream);
    hipMemsetAsync(c1a, 0, nH*sizeof(float), stream);

    pack_B1<<<28, 256, 0, stream>>>(Wh1, Wx1, b1, Bp);

    ushort_t *hcur = h1a, *hnxt = h1b;
    float    *ccur = c1a, *cnxt = c1b;
    for (int t=0; t<T1_; t+=2){
        lstm1_step2_mfma<<<dim3(9, B_), 256, 0, stream>>>(x, Bp, hcur, hnxt, ccur, cnxt, t);
        ushort_t* th = hcur; hcur = hnxt; hnxt = th;
        float*    tc = ccur; ccur = cnxt; cnxt = tc;
    }
    lstm2_mfma<<<dim3(B_), 256, 0, stream>>>(hcur, Wh2, Wx2, b2, x3);
    decoder_kernel<<<dim3(B_), 256, 0, stream>>>(x3, Wq,bq,Wk,bk,Wv,bv,Wo,bo,
                                                 g1,be1,W1,bf1,W2,bf2,g2,be2, x4);
    head_kernel<<<dim3(63, 128), 256, 0, stream>>>(x4, Wd, bd, (float*)d_out);
}

// Round 4
// 1281.842 us; speedup vs baseline: 7.8074x; 1.5582x over previous
//
#include <hip/hip_runtime.h>
#include <hip/hip_bf16.h>
#include <math.h>

#define B_  32
#define T1_ 128
#define L1_ 543
#define T2_ 543
#define VOCAB_ 32000

typedef __attribute__((ext_vector_type(8))) short bf16x8;
typedef __attribute__((ext_vector_type(4))) float f32x4;
typedef unsigned short ushort_t;

__device__ __forceinline__ short f2bf(float f){
    union { float f; unsigned u; } v; v.f = f;
    unsigned r = v.u + 0x7FFFu + ((v.u >> 16) & 1u);
    return (short)(r >> 16);
}
__device__ __forceinline__ float frcp_(float x){
    float r; asm("v_rcp_f32 %0, %1" : "=v"(r) : "v"(x));
    return r * (2.0f - x*r);   // one Newton step
}
__device__ __forceinline__ float fsig(float x){ return frcp_(1.0f + __expf(-x)); }

// ================= prepack Wh1/Wx1/b1 into MFMA B-fragment layout (bf16) =================
__global__ __launch_bounds__(256) void pack_B1(
    const float* __restrict__ Wh1,  // (3,64,256)
    const float* __restrict__ Wx1,  // (3,3,256)
    const float* __restrict__ b1,   // (256)
    short* __restrict__ Bp)         // 7*16*64*8 shorts
{
    int id = blockIdx.x*256 + threadIdx.x;
    if (id >= 7*16*64) return;
    int kt  = id >> 10;
    int rem = id & 1023;
    int nt  = rem >> 6;
    int lane= rem & 63;
    int j = nt*16 + (lane & 15);
    int g = lane >> 4;
    bf16x8 o;
    #pragma unroll
    for (int i=0;i<8;++i){
        int kl = 8*g + i;
        float v = 0.f;
        if (kt < 6){
            int tap = kt >> 1, ch = (kt & 1)*32 + kl;
            v = Wh1[(tap*64 + ch)*256 + j];
        } else {
            if (kl < 9){ int tap = kl/3, ch = kl - 3*tap; v = Wx1[(tap*3 + ch)*256 + j]; }
            else if (kl == 9) v = b1[j];
        }
        o[i] = f2bf(v);
    }
    *(bf16x8*)(Bp + (size_t)id*8) = o;
}

// ================= Stage 1: ConvLSTM1D #1, MFMA, 2 steps/launch, 512 threads =================
// grid (8, 32), block 512 (8 waves). Chunk = 68 interior rows.
// wave: cq = wave&3 (ch group, ch=16cq+ln), mgrp = wave>>2 (M-tile group: {0,1,2} / {3,4}).
__global__ __launch_bounds__(512, 2) void lstm1_step2_mfma(
    const float* __restrict__ x,       // (B,128,543,3) fp32
    const short* __restrict__ Bp,      // packed B frags
    const ushort_t* __restrict__ h_in, // (B,543,64) bf16 = h(t-1)
    ushort_t* __restrict__ h_out,      // (B,543,64) bf16 = h(t+1)
    const float* __restrict__ c_in,    // (B,543,64) fp32 = c(t-1)
    float* __restrict__ c_out,         // (B,543,64) fp32 = c(t+1)
    int t)
{
    // one blob so masked-tile overreads stay inside allocated LDS
    __shared__ char smem_[40960];
    short* hA = (short*)smem_;            // 72 rows x 72  (rows <-> l0-2+r)
    short* hB = hA + 5184;                // 70 rows x 72  (rows <-> l0-1+r)
    short* xA = hA + 10224;               // 72 x 4
    short* xB = hA + 10512;               // 70 x 4
    float* cL = (float*)(smem_ + 21584);  // 70 rows x 68  (rows <-> l0-1+r)

    const int tid = threadIdx.x;
    const int wave = tid>>6, lane = tid&63, g = lane>>4, ln = lane&15;
    const int cq = wave&3, mgrp = wave>>2;
    const int b = blockIdx.y, l0 = blockIdx.x*68;
    const int ch = 16*cq + ln;
    const int NT = mgrp ? 2 : 3;
    const int mt0 = mgrp*3;

    // early c(t-1) loads (consumed in gate phase A)
    float cr[3][4];
    #pragma unroll
    for (int ti=0; ti<3; ++ti)
      #pragma unroll
      for (int r=0; r<4; ++r){
        cr[ti][r] = 0.f;
        if (ti < NT){
            int mA = (mt0+ti)*16 + 4*g + r;
            int l = l0 - 1 + mA;
            if (mA < 70 && l >= 0 && l < L1_)
                cr[ti][r] = c_in[((size_t)b*L1_ + l)*64 + ch];
        }
      }

    // B fragments (shared by both steps)
    bf16x8 Bf[7][4];
    #pragma unroll
    for (int kt=0; kt<7; ++kt)
      #pragma unroll
      for (int gt=0; gt<4; ++gt)
        Bf[kt][gt] = *(const bf16x8*)(Bp + (size_t)(((kt*16 + (gt*4 + cq))*64) + lane)*8);

    // stage h(t-1): 72 rows x 64 ch bf16
    const ushort_t* hb = h_in + (size_t)b*(L1_*64);
    for (int u=tid; u<72*8; u+=512){
        int row = u>>3, c8 = u&7;
        int l = l0 - 2 + row;
        uint4 v = make_uint4(0u,0u,0u,0u);
        if (l >= 0 && l < L1_) v = *(const uint4*)(hb + (size_t)l*64 + c8*8);
        *(uint4*)(hA + row*72 + c8*8) = v;
    }
    // stage x(t) 72 rows, x(t+1) 70 rows
    const float* xt = x + ((size_t)b*T1_ + t)*(L1_*3);
    for (int u=tid; u<72*3; u+=512){
        int row = u/3, c = u - 3*row;
        int l = l0 - 2 + row;
        xA[row*4+c] = f2bf((l>=0 && l<L1_) ? xt[l*3+c] : 0.f);
    }
    for (int u=tid; u<70*3; u+=512){
        int row = u/3, c = u - 3*row;
        int l = l0 - 1 + row;
        xB[row*4+c] = f2bf((l>=0 && l<L1_) ? xt[L1_*3 + l*3+c] : 0.f);
    }
    __syncthreads();

    f32x4 zero4 = {0.f,0.f,0.f,0.f};
    // ---- step A: z(t) for this wave's M-tiles (output rows mA<70 <-> l0-1..l0+68) ----
    {
        f32x4 acc[3][4];
        #pragma unroll
        for (int ti=0; ti<3; ++ti)
          #pragma unroll
          for (int gt=0; gt<4; ++gt) acc[ti][gt] = zero4;

        #pragma unroll
        for (int ti=0; ti<3; ++ti) if (ti < NT){
            const int rbase = (mt0+ti)*16 + ln;
            #pragma unroll
            for (int kt=0; kt<6; ++kt){
                int tap = kt >> 1;
                bf16x8 a = *(const bf16x8*)(hA + (rbase + tap)*72 + (kt&1)*32 + 8*g);
                #pragma unroll
                for (int gt=0; gt<4; ++gt)
                    acc[ti][gt] = __builtin_amdgcn_mfma_f32_16x16x32_bf16(a, Bf[kt][gt], acc[ti][gt], 0,0,0);
            }
            bf16x8 a6;
            #pragma unroll
            for (int i=0;i<8;++i) a6[i] = 0;
            if (g == 0){
                #pragma unroll
                for (int i=0;i<8;++i){ int tap = i/3, c = i - 3*tap; a6[i] = xA[(rbase+tap)*4 + c]; }
            } else if (g == 1){
                a6[0] = xA[(rbase+2)*4 + 2];
                a6[1] = (short)0x3F80;
            }
            #pragma unroll
            for (int gt=0; gt<4; ++gt)
                acc[ti][gt] = __builtin_amdgcn_mfma_f32_16x16x32_bf16(a6, Bf[6][gt], acc[ti][gt], 0,0,0);
        }

        // gate phase A: h(t) -> hB (bf16), c(t) -> cL (fp32)
        #pragma unroll
        for (int ti=0; ti<3; ++ti) if (ti < NT)
          #pragma unroll
          for (int r=0; r<4; ++r){
            int mA = (mt0+ti)*16 + 4*g + r;
            if (mA < 70){
                int l = l0 - 1 + mA;
                float cv = 0.f, hv = 0.f;
                if (l >= 0 && l < L1_){
                    float iv = fsig(acc[ti][0][r]);
                    float fv = fsig(acc[ti][1][r]);
                    float gv = fmaxf(acc[ti][2][r], 0.f);
                    float ov = fsig(acc[ti][3][r]);
                    cv = fv*cr[ti][r] + iv*gv;
                    hv = ov * fmaxf(cv, 0.f);
                }
                cL[mA*68 + ch] = cv;
                hB[mA*72 + ch] = f2bf(hv);
            }
          }
    }
    __syncthreads();

    // ---- step B: z(t+1) interior rows (mB<68) ----
    {
        f32x4 acc[3][4];
        #pragma unroll
        for (int ti=0; ti<3; ++ti)
          #pragma unroll
          for (int gt=0; gt<4; ++gt) acc[ti][gt] = zero4;

        #pragma unroll
        for (int ti=0; ti<3; ++ti) if (ti < NT){
            const int rbase = (mt0+ti)*16 + ln;
            #pragma unroll
            for (int kt=0; kt<6; ++kt){
                int tap = kt >> 1;
                bf16x8 a = *(const bf16x8*)(hB + (rbase + tap)*72 + (kt&1)*32 + 8*g);
                #pragma unroll
                for (int gt=0; gt<4; ++gt)
                    acc[ti][gt] = __builtin_amdgcn_mfma_f32_16x16x32_bf16(a, Bf[kt][gt], acc[ti][gt], 0,0,0);
            }
            bf16x8 a6;
            #pragma unroll
            for (int i=0;i<8;++i) a6[i] = 0;
            if (g == 0){
                #pragma unroll
                for (int i=0;i<8;++i){ int tap = i/3, c = i - 3*tap; a6[i] = xB[(rbase+tap)*4 + c]; }
            } else if (g == 1){
                a6[0] = xB[(rbase+2)*4 + 2];
                a6[1] = (short)0x3F80;
            }
            #pragma unroll
            for (int gt=0; gt<4; ++gt)
                acc[ti][gt] = __builtin_amdgcn_mfma_f32_16x16x32_bf16(a6, Bf[6][gt], acc[ti][gt], 0,0,0);
        }

        // gate phase B: write h(t+1) bf16 + c(t+1) fp32 to global (interior only)
        #pragma unroll
        for (int ti=0; ti<3; ++ti) if (ti < NT)
          #pragma unroll
          for (int r=0; r<4; ++r){
            int mB = (mt0+ti)*16 + 4*g + r;
            int l = l0 + mB;
            if (mB < 68 && l < L1_){
                float ct = cL[(mB+1)*68 + ch];
                float iv = fsig(acc[ti][0][r]);
                float fv = fsig(acc[ti][1][r]);
                float gv = fmaxf(acc[ti][2][r], 0.f);
                float ov = fsig(acc[ti][3][r]);
                float cv = fv*ct + iv*gv;
                float hv = ov * fmaxf(cv, 0.f);
                size_t idx = ((size_t)b*L1_ + l)*64 + ch;
                c_out[idx] = cv;
                h_out[idx] = (ushort_t)f2bf(hv);
            }
          }
    }
}

// ================= Stage 2: ConvLSTM1D #2, MFMA, persistent, 512 threads =================
// wave: s = wave&3 (row strip 16s..16s+15), q = wave>>2 (ch half, ch=16q+ln).
// nt set for wave: {q, q+2, q+4, q+6} = gate gi at nt=2*gi+q.
__global__ __launch_bounds__(512) void lstm2_mfma(
    const ushort_t* __restrict__ x2, // (B,543,64) bf16
    const float* __restrict__ Wh2,   // (3,32,128)
    const float* __restrict__ Wx2,   // (3,1,128)
    const float* __restrict__ b2,    // (128)
    float* __restrict__ out)         // (B,64,32)
{
    __shared__ short hs[66*40];
    __shared__ short xsb[66];
    const int tid = threadIdx.x;
    const int wave = tid>>6, lane = tid&63, g = lane>>4, ln = lane&15;
    const int s = wave&3, q = wave>>2;
    const int b = blockIdx.x;

    bf16x8 Bf[4][4];
    #pragma unroll
    for (int gi=0; gi<4; ++gi){
        int j = (2*gi + q)*16 + ln;
        #pragma unroll
        for (int kt=0; kt<3; ++kt){
            bf16x8 o;
            #pragma unroll
            for (int i=0;i<8;++i) o[i] = f2bf(Wh2[(kt*32 + 8*g + i)*128 + j]);
            Bf[kt][gi] = o;
        }
        bf16x8 o;
        #pragma unroll
        for (int i=0;i<8;++i) o[i] = 0;
        if (g==0){
            o[0]=f2bf(Wx2[0*128+j]); o[1]=f2bf(Wx2[1*128+j]); o[2]=f2bf(Wx2[2*128+j]);
            o[3]=f2bf(b2[j]);
        }
        Bf[3][gi] = o;
    }

    for (int i=tid; i<66*40; i+=512) hs[i]=0;
    if (tid<66) xsb[tid]=0;
    float creg[4];
    #pragma unroll
    for (int i=0;i<4;++i) creg[i]=0.f;

    const ushort_t* xb = x2 + (size_t)b*(T2_*64);
    ushort_t xreg = (tid < 64) ? xb[tid] : (ushort_t)0;   // prefetch t=0
    __syncthreads();

    const int lA = 16*s + ln;
    const int chn = 16*q + ln;

    for (int t=0; t<T2_; ++t){
        if (tid < 64) xsb[1+tid] = (short)xreg;
        __syncthreads();            // h(t-1) writes + x row visible
        if (tid < 64 && t+1 < T2_) xreg = xb[(size_t)(t+1)*64 + tid];  // prefetch next

        f32x4 acc[4];
        f32x4 zero4 = {0.f,0.f,0.f,0.f};
        #pragma unroll
        for (int gi=0; gi<4; ++gi) acc[gi] = zero4;

        #pragma unroll
        for (int kt=0; kt<3; ++kt){
            bf16x8 a = *(const bf16x8*)(hs + (lA + kt)*40 + 8*g);
            #pragma unroll
            for (int gi=0; gi<4; ++gi)
                acc[gi] = __builtin_amdgcn_mfma_f32_16x16x32_bf16(a, Bf[kt][gi], acc[gi], 0,0,0);
        }
        {
            bf16x8 a3;
            #pragma unroll
            for (int i=0;i<8;++i) a3[i] = 0;
            if (g==0){
                a3[0]=xsb[lA]; a3[1]=xsb[lA+1]; a3[2]=xsb[lA+2];
                a3[3]=(short)0x3F80;
            }
            #pragma unroll
            for (int gi=0; gi<4; ++gi)
                acc[gi] = __builtin_amdgcn_mfma_f32_16x16x32_bf16(a3, Bf[3][gi], acc[gi], 0,0,0);
        }
        __syncthreads();            // all A-reads done before h overwrite

        #pragma unroll
        for (int r=0; r<4; ++r){
            int l = 16*s + 4*g + r;
            float iv = fsig(acc[0][r]);
            float fv = fsig(acc[1][r]);
            float gv = fmaxf(acc[2][r], 0.f);
            float ov = fsig(acc[3][r]);
            float cv = fv*creg[r] + iv*gv;
            creg[r] = cv;
            float hv = ov * fmaxf(cv, 0.f);
            hs[(1+l)*40 + chn] = f2bf(hv);
            if (t == T2_-1) out[(size_t)b*2048 + l*32 + chn] = hv;
        }
    }
}

// ================= Transformer decoder, 1 WG per batch =================
__global__ __launch_bounds__(256) void decoder_kernel(
    const float* __restrict__ xin,
    const float* __restrict__ Wq, const float* __restrict__ bq,
    const float* __restrict__ Wk, const float* __restrict__ bk,
    const float* __restrict__ Wv, const float* __restrict__ bv,
    const float* __restrict__ Wo, const float* __restrict__ bo,
    const float* __restrict__ g1, const float* __restrict__ be1,
    const float* __restrict__ W1, const float* __restrict__ bf1,
    const float* __restrict__ W2, const float* __restrict__ bf2,
    const float* __restrict__ g2, const float* __restrict__ be2,
    float* __restrict__ xout)
{
    __shared__ float smem[16384];
    float* sx  = smem;
    float* sq  = smem + 2048;
    float* sk  = smem + 4096;
    float* sv  = smem + 6144;
    float* so  = smem + 8192;
    float* sy  = smem + 10240;
    float* sff = smem + 12288;

    const int b = blockIdx.x;
    const int tid = threadIdx.x;

    for (int i=tid; i<2048; i+=256) sx[i] = xin[(size_t)b*2048 + i];
    __syncthreads();

    for (int i=tid; i<2048; i+=256){
        int s = i >> 5, j = i & 31;
        float aq = bq[j], ak = bk[j], av = bv[j];
        for (int d=0; d<32; ++d){
            float xv = sx[s*32+d];
            aq = fmaf(xv, Wq[d*32+j], aq);
            ak = fmaf(xv, Wk[d*32+j], ak);
            av = fmaf(xv, Wv[d*32+j], av);
        }
        sq[i]=aq; sk[i]=ak; sv[i]=av;
    }
    __syncthreads();

    if (tid < 128){
        int h = tid >> 6, si = tid & 63;
        const int o = h*16;
        float qv[16];
        #pragma unroll
        for (int kk=0; kk<16; ++kk) qv[kk] = sq[si*32 + o + kk];
        float mx = -1e30f;
        for (int ti=0; ti<=si; ++ti){
            float sc = 0.f;
            #pragma unroll
            for (int kk=0; kk<16; ++kk) sc = fmaf(qv[kk], sk[ti*32+o+kk], sc);
            mx = fmaxf(mx, sc*0.25f);
        }
        float sum = 0.f;
        float accv[16];
        #pragma unroll
        for (int kk=0; kk<16; ++kk) accv[kk]=0.f;
        for (int ti=0; ti<=si; ++ti){
            float sc = 0.f;
            #pragma unroll
            for (int kk=0; kk<16; ++kk) sc = fmaf(qv[kk], sk[ti*32+o+kk], sc);
            float p = expf(sc*0.25f - mx);
            sum += p;
            #pragma unroll
            for (int kk=0; kk<16; ++kk) accv[kk] = fmaf(p, sv[ti*32+o+kk], accv[kk]);
        }
        float inv = 1.f/sum;
        #pragma unroll
        for (int kk=0; kk<16; ++kk) so[si*32 + o + kk] = accv[kk]*inv;
    }
    __syncthreads();

    for (int i=tid; i<2048; i+=256){
        int s = i>>5, d = i&31;
        float a = bo[d];
        for (int j=0; j<32; ++j) a = fmaf(so[s*32+j], Wo[j*32+d], a);
        sy[i] = sx[i] + a;
    }
    __syncthreads();
    if (tid < 64){
        float mu=0.f;
        for (int d=0; d<32; ++d) mu += sy[tid*32+d];
        mu *= (1.f/32.f);
        float var=0.f;
        for (int d=0; d<32; ++d){ float dd = sy[tid*32+d]-mu; var = fmaf(dd,dd,var); }
        var *= (1.f/32.f);
        float rs = rsqrtf(var + 1e-5f);
        for (int d=0; d<32; ++d) sy[tid*32+d] = (sy[tid*32+d]-mu)*rs*g1[d] + be1[d];
    }
    __syncthreads();
    for (int i=tid; i<4096; i+=256){
        int s = i>>6, ff = i&63;
        float a = bf1[ff];
        for (int d=0; d<32; ++d) a = fmaf(sy[s*32+d], W1[d*64+ff], a);
        sff[i] = fmaxf(a, 0.f);
    }
    __syncthreads();
    for (int i=tid; i<2048; i+=256){
        int s=i>>5, d=i&31;
        float a = bf2[d];
        for (int ff=0; ff<64; ++ff) a = fmaf(sff[s*64+ff], W2[ff*32+d], a);
        sx[i] = sy[i] + a;
    }
    __syncthreads();
    if (tid < 64){
        float mu=0.f;
        for (int d=0; d<32; ++d) mu += sx[tid*32+d];
        mu *= (1.f/32.f);
        float var=0.f;
        for (int d=0; d<32; ++d){ float dd = sx[tid*32+d]-mu; var = fmaf(dd,dd,var); }
        var *= (1.f/32.f);
        float rs = rsqrtf(var + 1e-5f);
        for (int d=0; d<32; ++d)
            xout[(size_t)b*2048 + tid*32 + d] = (sx[tid*32+d]-mu)*rs*g2[d] + be2[d];
    }
}

// ================= Vocab head: 512-row x 512-col tiles, Wd cols in registers =================
// grid (63, 4), block 256. Traffic: Wd 4x4MB + x 16MB + out 262MB ~= 294MB.
__global__ __launch_bounds__(256) void head_kernel(
    const float* __restrict__ xin,  // (2048, 32)
    const float* __restrict__ Wd,   // (32, 32000)
    const float* __restrict__ bd,   // (32000)
    float* __restrict__ out)        // (2048, 32000)
{
    __shared__ float sx[512*32];    // 64 KB
    const int r0 = blockIdx.y * 512;
    const int c0 = blockIdx.x * 512;
    const int tid = threadIdx.x;
    for (int u=tid; u<512*8; u+=256){
        int row = u>>3, c8 = u&7;
        *(float4*)(sx + row*32 + c8*4) = *(const float4*)(xin + (size_t)(r0+row)*32 + c8*4);
    }
    __syncthreads();
    int c = c0 + tid*2;
    if (c >= VOCAB_) return;
    float w0[32], w1[32];
    #pragma unroll
    for (int d=0; d<32; ++d){
        w0[d] = Wd[(size_t)d*VOCAB_ + c];
        w1[d] = Wd[(size_t)d*VOCAB_ + c + 1];
    }
    float b0 = bd[c], b1 = bd[c+1];
    for (int r=0; r<512; ++r){
        const float* xr = sx + r*32;
        float a0 = b0, a1 = b1;
        #pragma unroll
        for (int d=0; d<32; ++d){
            float xv = xr[d];
            a0 = fmaf(xv, w0[d], a0);
            a1 = fmaf(xv, w1[d], a1);
        }
        *reinterpret_cast<float2*>(&out[(size_t)(r0+r)*VOCAB_ + c]) = make_float2(a0, a1);
    }
}

// ================= launch =================
extern "C" void kernel_launch(void* const* d_in, const int* in_sizes, int n_in,
                              void* d_out, int out_size, void* d_ws, size_t ws_size,
                              hipStream_t stream)
{
    const float* x   = (const float*)d_in[0];
    const float* Wx1 = (const float*)d_in[1];
    const float* Wh1 = (const float*)d_in[2];
    const float* b1  = (const float*)d_in[3];
    const float* Wx2 = (const float*)d_in[4];
    const float* Wh2 = (const float*)d_in[5];
    const float* b2  = (const float*)d_in[6];
    const float* Wq  = (const float*)d_in[7];
    const float* bq  = (const float*)d_in[8];
    const float* Wk  = (const float*)d_in[9];
    const float* bk  = (const float*)d_in[10];
    const float* Wv  = (const float*)d_in[11];
    const float* bv  = (const float*)d_in[12];
    const float* Wo  = (const float*)d_in[13];
    const float* bo  = (const float*)d_in[14];
    const float* g1  = (const float*)d_in[15];
    const float* be1 = (const float*)d_in[16];
    const float* W1  = (const float*)d_in[17];
    const float* bf1 = (const float*)d_in[18];
    const float* W2  = (const float*)d_in[19];
    const float* bf2 = (const float*)d_in[20];
    const float* g2  = (const float*)d_in[21];
    const float* be2 = (const float*)d_in[22];
    const float* Wd  = (const float*)d_in[23];
    const float* bd  = (const float*)d_in[24];

    const size_t nH = (size_t)B_ * L1_ * 64;    // 1,112,064 elements per state buffer
    float* ws = (float*)d_ws;
    size_t ws_floats = ws_size / sizeof(float);
    float* x3 = ws;                          // 65536 floats
    float* x4 = ws + 65536;                  // 65536 floats
    short* Bp = (short*)(ws + 131072);       // 57344 shorts = 28672 floats
    const size_t base_f = 131072 + 28672;
    const size_t need_f = base_f + nH + 2*nH; // 2 bf16 bufs (nH shorts = nH/2*2 floats) + 2 f32 bufs
    float* statebase;
    if (ws_floats >= need_f) statebase = ws + base_f;
    else                     statebase = (float*)d_out;    // 262MB scratch, consumed before head writes
    ushort_t* h1a = (ushort_t*)statebase;                  // nH bf16
    ushort_t* h1b = h1a + nH;                              // nH bf16
    float*    c1a = (float*)(h1b + nH);                    // nH f32
    float*    c1b = c1a + nH;                              // nH f32

    hipMemsetAsync(h1a, 0, nH*sizeof(ushort_t), stream);
    hipMemsetAsync(c1a, 0, nH*sizeof(float), stream);

    pack_B1<<<28, 256, 0, stream>>>(Wh1, Wx1, b1, Bp);

    ushort_t *hcur = h1a, *hnxt = h1b;
    float    *ccur = c1a, *cnxt = c1b;
    for (int t=0; t<T1_; t+=2){
        lstm1_step2_mfma<<<dim3(8, B_), 512, 0, stream>>>(x, Bp, hcur, hnxt, ccur, cnxt, t);
        ushort_t* th = hcur; hcur = hnxt; hnxt = th;
        float*    tc = ccur; ccur = cnxt; cnxt = tc;
    }
    lstm2_mfma<<<dim3(B_), 512, 0, stream>>>(hcur, Wh2, Wx2, b2, x3);
    decoder_kernel<<<dim3(B_), 256, 0, stream>>>(x3, Wq,bq,Wk,bk,Wv,bv,Wo,bo,
                                                 g1,be1,W1,bf1,W2,bf2,g2,be2, x4);
    head_kernel<<<dim3(63, 4), 256, 0, stream>>>(x4, Wd, bd, (float*)d_out);
}

// Round 9
// 1086.503 us; speedup vs baseline: 9.2110x; 1.1798x over previous
//
#include <hip/hip_runtime.h>
#include <hip/hip_bf16.h>
#include <math.h>

#define B_  32
#define T1_ 128
#define L1_ 543
#define T2_ 543
#define VOCAB_ 32000

typedef __attribute__((ext_vector_type(8))) short bf16x8;
typedef __attribute__((ext_vector_type(4))) float f32x4;
typedef unsigned short ushort_t;

__device__ __forceinline__ short f2bf(float f){
    union { float f; unsigned u; } v; v.f = f;
    unsigned r = v.u + 0x7FFFu + ((v.u >> 16) & 1u);
    return (short)(r >> 16);
}
__device__ __forceinline__ float frcp_(float x){
    float r; asm("v_rcp_f32 %0, %1" : "=v"(r) : "v"(x));
    return r * (2.0f - x*r);   // one Newton step
}
// classic sigmoid — PROVEN (rounds 2-4). Do NOT replace with hand-emitted
// v_exp asm: rounds 5-8 showed inline-asm trans ops NaN (hazard not inserted
// around opaque asm). __expf goes through the compiler -> hazards handled.
__device__ __forceinline__ float fsig(float x){ return frcp_(1.0f + __expf(-x)); }

// ================= prepack Wh1/Wx1/b1 into MFMA B-fragment layout (bf16), UNSCALED =================
__global__ __launch_bounds__(256) void pack_B1(
    const float* __restrict__ Wh1,  // (3,64,256)
    const float* __restrict__ Wx1,  // (3,3,256)
    const float* __restrict__ b1,   // (256)
    short* __restrict__ Bp)         // 7*16*64*8 shorts
{
    int id = blockIdx.x*256 + threadIdx.x;
    if (id >= 7*16*64) return;
    int kt  = id >> 10;
    int rem = id & 1023;
    int nt  = rem >> 6;
    int lane= rem & 63;
    int j = nt*16 + (lane & 15);
    int g = lane >> 4;
    bf16x8 o;
    #pragma unroll
    for (int i=0;i<8;++i){
        int kl = 8*g + i;
        float v = 0.f;
        if (kt < 6){
            int tap = kt >> 1, ch = (kt & 1)*32 + kl;
            v = Wh1[(tap*64 + ch)*256 + j];
        } else {
            if (kl < 9){ int tap = kl/3, ch = kl - 3*tap; v = Wx1[(tap*3 + ch)*256 + j]; }
            else if (kl == 9) v = b1[j];
        }
        o[i] = f2bf(v);
    }
    *(bf16x8*)(Bp + (size_t)id*8) = o;
}

// ================= Stage 1: ConvLSTM1D #1, MFMA, FOUR timesteps per launch =================
// grid (8, 32), block 512 (8 waves). Chunk = 68 interior rows, halo 4.
// FIXED row<->l mapping for ALL buffers/steps: row r <-> l = l0-4+r.
// MFMA m-index u reads rows u..u+2 (centered row u+1) -> gate output of m-index u
// is STORED AT ROW u+1. Valid trapezoid at sub-step s: rows [1+s, 75-s);
// s=3 -> rows [4,72) = l in [l0, l0+68) = exact interior. Geometry verified 3x.
// wave: cq = wave&3 (ch group, ch=16cq+ln), mgrp = wave>>2 (M-tiles {0,1,2}/{3,4}).
__global__ __launch_bounds__(512) void lstm1_step4_mfma(
    const float* __restrict__ x,       // (B,128,543,3) fp32
    const short* __restrict__ Bp,      // packed B frags
    const ushort_t* __restrict__ h_in, // (B,543,64) bf16 = h(t-1)
    ushort_t* __restrict__ h_out,      // (B,543,64) bf16 = h(t+3)
    const float* __restrict__ c_in,    // (B,543,64) fp32 = c(t-1)
    float* __restrict__ c_out,         // (B,543,64) fp32 = c(t+3)
    int t)
{
    __shared__ short h0s[82*72];       // 82 rows so tile-5 A-reads (rows<=81) stay in-buffer
    __shared__ short h1s[82*72];
    __shared__ short xs4[4*82*4];      // x(t..t+3), rows [0,82), 3ch+pad

    const int tid = threadIdx.x;
    const int wave = tid>>6, lane = tid&63, g = lane>>4, ln = lane&15;
    const int cq = wave&3, mgrp = wave>>2;
    const int b = blockIdx.y, l0 = blockIdx.x*68;
    const int ch = 16*cq + ln;
    const int NT = mgrp ? 2 : 3;
    const int mt0 = mgrp*3;

    // c(t-1) -> registers (long-latency, issue first). Row = m-index + 1.
    float cr[3][4];
    #pragma unroll
    for (int ti=0; ti<3; ++ti)
      #pragma unroll
      for (int rr=0; rr<4; ++rr){
        cr[ti][rr] = 0.f;
        if (ti < NT){
            int row = (mt0+ti)*16 + 4*g + rr + 1;
            int l = l0 - 4 + row;
            if (row < 75 && l >= 0 && l < L1_)
                cr[ti][rr] = c_in[((size_t)b*L1_ + l)*64 + ch];
        }
      }

    // B fragments (shared by all 4 sub-steps)
    bf16x8 Bf[7][4];
    #pragma unroll
    for (int kt=0; kt<7; ++kt)
      #pragma unroll
      for (int gt=0; gt<4; ++gt)
        Bf[kt][gt] = *(const bf16x8*)(Bp + (size_t)(((kt*16 + (gt*4 + cq))*64) + lane)*8);

    // stage h(t-1) rows [0,76) -> h0s; zero h0s rows [76,82); zero ALL h1s
    const ushort_t* hb = h_in + (size_t)b*(L1_*64);
    for (int u=tid; u<76*8; u+=512){
        int row = u>>3, c8 = u&7;
        int l = l0 - 4 + row;
        uint4 v = make_uint4(0u,0u,0u,0u);
        if (l >= 0 && l < L1_) v = *(const uint4*)(hb + (size_t)l*64 + c8*8);
        *(uint4*)(h0s + row*72 + c8*8) = v;
    }
    for (int u=tid; u<216;  u+=512) ((int*)(h0s + 76*72))[u] = 0;
    for (int u=tid; u<2952; u+=512) ((int*)h1s)[u] = 0;
    // stage x(t..t+3), rows [0,82)
    const float* xb0 = x + ((size_t)b*T1_ + t)*(L1_*3);
    for (int u=tid; u<4*82*3; u+=512){
        int st = u/(82*3), rem = u - st*(82*3);
        int row = rem/3, c = rem - 3*row;
        int l = l0 - 4 + row;
        xs4[st*328 + row*4 + c] = f2bf((l>=0 && l<L1_) ? xb0[(size_t)st*(L1_*3) + l*3 + c] : 0.f);
    }
    __syncthreads();

    f32x4 zero4 = {0.f,0.f,0.f,0.f};
    for (int s=0; s<4; ++s){
        const short* src = (s&1) ? h1s : h0s;
        short*       dst = (s&1) ? h0s : h1s;
        const short* xv  = xs4 + s*328;

        f32x4 acc[3][4];
        #pragma unroll
        for (int ti=0; ti<3; ++ti)
          #pragma unroll
          for (int gt=0; gt<4; ++gt) acc[ti][gt] = zero4;

        #pragma unroll
        for (int ti=0; ti<3; ++ti) if (ti < NT){
            const int rbase = (mt0+ti)*16 + ln;
            #pragma unroll
            for (int kt=0; kt<6; ++kt){
                int tap = kt >> 1;
                bf16x8 a = *(const bf16x8*)(src + (rbase + tap)*72 + (kt&1)*32 + 8*g);
                #pragma unroll
                for (int gt=0; gt<4; ++gt)
                    acc[ti][gt] = __builtin_amdgcn_mfma_f32_16x16x32_bf16(a, Bf[kt][gt], acc[ti][gt], 0,0,0);
            }
            bf16x8 a6;
            #pragma unroll
            for (int i=0;i<8;++i) a6[i] = 0;
            if (g == 0){
                #pragma unroll
                for (int i=0;i<8;++i){ int tap = i/3, c = i - 3*tap; a6[i] = xv[(rbase+tap)*4 + c]; }
            } else if (g == 1){
                a6[0] = xv[(rbase+2)*4 + 2];
                a6[1] = (short)0x3F80;
            }
            #pragma unroll
            for (int gt=0; gt<4; ++gt)
                acc[ti][gt] = __builtin_amdgcn_mfma_f32_16x16x32_bf16(a6, Bf[6][gt], acc[ti][gt], 0,0,0);
        }

        // gates: m-index u stored at row u+1; valid rows [1+s, 75-s), l in [0,543)
        #pragma unroll
        for (int ti=0; ti<3; ++ti) if (ti < NT)
          #pragma unroll
          for (int rr=0; rr<4; ++rr){
            int row = (mt0+ti)*16 + 4*g + rr + 1;
            int l = l0 - 4 + row;
            if (row >= 1+s && row < 75-s && l >= 0 && l < L1_){
                float iv = fsig(acc[ti][0][rr]);
                float fv = fsig(acc[ti][1][rr]);
                float gv = fmaxf(acc[ti][2][rr], 0.f);
                float ov = fsig(acc[ti][3][rr]);
                float cv = fv*cr[ti][rr] + iv*gv;
                cr[ti][rr] = cv;
                float hv = ov * fmaxf(cv, 0.f);
                if (s < 3){
                    dst[row*72 + ch] = f2bf(hv);
                } else {
                    size_t idx = ((size_t)b*L1_ + l)*64 + ch;
                    c_out[idx] = cv;
                    h_out[idx] = (ushort_t)f2bf(hv);
                }
            }
          }
        if (s < 3) __syncthreads();
    }
}

// ================= Stage 2: ConvLSTM1D #2, MFMA, persistent (round-4 VERBATIM, PASSED) =================
// wave: s = wave&3 (row strip), q = wave>>2 (ch half). gate gi at N-tile nt=2*gi+q.
__global__ __launch_bounds__(512) void lstm2_mfma(
    const ushort_t* __restrict__ x2, // (B,543,64) bf16
    const float* __restrict__ Wh2,   // (3,32,128)
    const float* __restrict__ Wx2,   // (3,1,128)
    const float* __restrict__ b2,    // (128)
    float* __restrict__ out)         // (B,64,32)
{
    __shared__ short hs[66*40];
    __shared__ short xsb[66];
    const int tid = threadIdx.x;
    const int wave = tid>>6, lane = tid&63, g = lane>>4, ln = lane&15;
    const int s = wave&3, q = wave>>2;
    const int b = blockIdx.x;

    bf16x8 Bf[4][4];
    #pragma unroll
    for (int gi=0; gi<4; ++gi){
        int j = (2*gi + q)*16 + ln;
        #pragma unroll
        for (int kt=0; kt<3; ++kt){
            bf16x8 o;
            #pragma unroll
            for (int i=0;i<8;++i) o[i] = f2bf(Wh2[(kt*32 + 8*g + i)*128 + j]);
            Bf[kt][gi] = o;
        }
        bf16x8 o;
        #pragma unroll
        for (int i=0;i<8;++i) o[i] = 0;
        if (g==0){
            o[0]=f2bf(Wx2[0*128+j]); o[1]=f2bf(Wx2[1*128+j]); o[2]=f2bf(Wx2[2*128+j]);
            o[3]=f2bf(b2[j]);
        }
        Bf[3][gi] = o;
    }

    for (int i=tid; i<66*40; i+=512) hs[i]=0;
    if (tid<66) xsb[tid]=0;
    float creg[4];
    #pragma unroll
    for (int i=0;i<4;++i) creg[i]=0.f;

    const ushort_t* xb = x2 + (size_t)b*(T2_*64);
    ushort_t xreg = (tid < 64) ? xb[tid] : (ushort_t)0;   // prefetch t=0
    __syncthreads();

    const int lA = 16*s + ln;
    const int chn = 16*q + ln;

    for (int t=0; t<T2_; ++t){
        if (tid < 64) xsb[1+tid] = (short)xreg;
        __syncthreads();            // h(t-1) writes + x row visible
        if (tid < 64 && t+1 < T2_) xreg = xb[(size_t)(t+1)*64 + tid];  // prefetch next

        f32x4 acc[4];
        f32x4 zero4 = {0.f,0.f,0.f,0.f};
        #pragma unroll
        for (int gi=0; gi<4; ++gi) acc[gi] = zero4;

        #pragma unroll
        for (int kt=0; kt<3; ++kt){
            bf16x8 a = *(const bf16x8*)(hs + (lA + kt)*40 + 8*g);
            #pragma unroll
            for (int gi=0; gi<4; ++gi)
                acc[gi] = __builtin_amdgcn_mfma_f32_16x16x32_bf16(a, Bf[kt][gi], acc[gi], 0,0,0);
        }
        {
            bf16x8 a3;
            #pragma unroll
            for (int i=0;i<8;++i) a3[i] = 0;
            if (g==0){
                a3[0]=xsb[lA]; a3[1]=xsb[lA+1]; a3[2]=xsb[lA+2];
                a3[3]=(short)0x3F80;
            }
            #pragma unroll
            for (int gi=0; gi<4; ++gi)
                acc[gi] = __builtin_amdgcn_mfma_f32_16x16x32_bf16(a3, Bf[3][gi], acc[gi], 0,0,0);
        }
        __syncthreads();            // all A-reads done before h overwrite

        #pragma unroll
        for (int r=0; r<4; ++r){
            int l = 16*s + 4*g + r;
            float iv = fsig(acc[0][r]);
            float fv = fsig(acc[1][r]);
            float gv = fmaxf(acc[2][r], 0.f);
            float ov = fsig(acc[3][r]);
            float cv = fv*creg[r] + iv*gv;
            creg[r] = cv;
            float hv = ov * fmaxf(cv, 0.f);
            hs[(1+l)*40 + chn] = f2bf(hv);
            if (t == T2_-1) out[(size_t)b*2048 + l*32 + chn] = hv;
        }
    }
}

// ================= Transformer decoder, 1 WG per batch =================
__global__ __launch_bounds__(256) void decoder_kernel(
    const float* __restrict__ xin,
    const float* __restrict__ Wq, const float* __restrict__ bq,
    const float* __restrict__ Wk, const float* __restrict__ bk,
    const float* __restrict__ Wv, const float* __restrict__ bv,
    const float* __restrict__ Wo, const float* __restrict__ bo,
    const float* __restrict__ g1, const float* __restrict__ be1,
    const float* __restrict__ W1, const float* __restrict__ bf1,
    const float* __restrict__ W2, const float* __restrict__ bf2,
    const float* __restrict__ g2, const float* __restrict__ be2,
    float* __restrict__ xout)
{
    __shared__ float smem[16384];
    float* sx  = smem;
    float* sq  = smem + 2048;
    float* sk  = smem + 4096;
    float* sv  = smem + 6144;
    float* so  = smem + 8192;
    float* sy  = smem + 10240;
    float* sff = smem + 12288;

    const int b = blockIdx.x;
    const int tid = threadIdx.x;

    for (int i=tid; i<2048; i+=256) sx[i] = xin[(size_t)b*2048 + i];
    __syncthreads();

    for (int i=tid; i<2048; i+=256){
        int s = i >> 5, j = i & 31;
        float aq = bq[j], ak = bk[j], av = bv[j];
        for (int d=0; d<32; ++d){
            float xv = sx[s*32+d];
            aq = fmaf(xv, Wq[d*32+j], aq);
            ak = fmaf(xv, Wk[d*32+j], ak);
            av = fmaf(xv, Wv[d*32+j], av);
        }
        sq[i]=aq; sk[i]=ak; sv[i]=av;
    }
    __syncthreads();

    if (tid < 128){
        int h = tid >> 6, si = tid & 63;
        const int o = h*16;
        float qv[16];
        #pragma unroll
        for (int kk=0; kk<16; ++kk) qv[kk] = sq[si*32 + o + kk];
        float mx = -1e30f;
        for (int ti=0; ti<=si; ++ti){
            float sc = 0.f;
            #pragma unroll
            for (int kk=0; kk<16; ++kk) sc = fmaf(qv[kk], sk[ti*32+o+kk], sc);
            mx = fmaxf(mx, sc*0.25f);
        }
        float sum = 0.f;
        float accv[16];
        #pragma unroll
        for (int kk=0; kk<16; ++kk) accv[kk]=0.f;
        for (int ti=0; ti<=si; ++ti){
            float sc = 0.f;
            #pragma unroll
            for (int kk=0; kk<16; ++kk) sc = fmaf(qv[kk], sk[ti*32+o+kk], sc);
            float p = expf(sc*0.25f - mx);
            sum += p;
            #pragma unroll
            for (int kk=0; kk<16; ++kk) accv[kk] = fmaf(p, sv[ti*32+o+kk], accv[kk]);
        }
        float inv = 1.f/sum;
        #pragma unroll
        for (int kk=0; kk<16; ++kk) so[si*32 + o + kk] = accv[kk]*inv;
    }
    __syncthreads();

    for (int i=tid; i<2048; i+=256){
        int s = i>>5, d = i&31;
        float a = bo[d];
        for (int j=0; j<32; ++j) a = fmaf(so[s*32+j], Wo[j*32+d], a);
        sy[i] = sx[i] + a;
    }
    __syncthreads();
    if (tid < 64){
        float mu=0.f;
        for (int d=0; d<32; ++d) mu += sy[tid*32+d];
        mu *= (1.f/32.f);
        float var=0.f;
        for (int d=0; d<32; ++d){ float dd = sy[tid*32+d]-mu; var = fmaf(dd,dd,var); }
        var *= (1.f/32.f);
        float rs = rsqrtf(var + 1e-5f);
        for (int d=0; d<32; ++d) sy[tid*32+d] = (sy[tid*32+d]-mu)*rs*g1[d] + be1[d];
    }
    __syncthreads();
    for (int i=tid; i<4096; i+=256){
        int s = i>>6, ff = i&63;
        float a = bf1[ff];
        for (int d=0; d<32; ++d) a = fmaf(sy[s*32+d], W1[d*64+ff], a);
        sff[i] = fmaxf(a, 0.f);
    }
    __syncthreads();
    for (int i=tid; i<2048; i+=256){
        int s=i>>5, d=i&31;
        float a = bf2[d];
        for (int ff=0; ff<64; ++ff) a = fmaf(sff[s*64+ff], W2[ff*32+d], a);
        sx[i] = sy[i] + a;
    }
    __syncthreads();
    if (tid < 64){
        float mu=0.f;
        for (int d=0; d<32; ++d) mu += sx[tid*32+d];
        mu *= (1.f/32.f);
        float var=0.f;
        for (int d=0; d<32; ++d){ float dd = sx[tid*32+d]-mu; var = fmaf(dd,dd,var); }
        var *= (1.f/32.f);
        float rs = rsqrtf(var + 1e-5f);
        for (int d=0; d<32; ++d)
            xout[(size_t)b*2048 + tid*32 + d] = (sx[tid*32+d]-mu)*rs*g2[d] + be2[d];
    }
}

// ================= Vocab head: 512-row x 512-col tiles, Wd cols in registers =================
__global__ __launch_bounds__(256) void head_kernel(
    const float* __restrict__ xin,  // (2048, 32)
    const float* __restrict__ Wd,   // (32, 32000)
    const float* __restrict__ bd,   // (32000)
    float* __restrict__ out)        // (2048, 32000)
{
    __shared__ float sx[512*32];    // 64 KB
    const int r0 = blockIdx.y * 512;
    const int c0 = blockIdx.x * 512;
    const int tid = threadIdx.x;
    for (int u=tid; u<512*8; u+=256){
        int row = u>>3, c8 = u&7;
        *(float4*)(sx + row*32 + c8*4) = *(const float4*)(xin + (size_t)(r0+row)*32 + c8*4);
    }
    __syncthreads();
    int c = c0 + tid*2;
    if (c >= VOCAB_) return;
    float w0[32], w1[32];
    #pragma unroll
    for (int d=0; d<32; ++d){
        w0[d] = Wd[(size_t)d*VOCAB_ + c];
        w1[d] = Wd[(size_t)d*VOCAB_ + c + 1];
    }
    float b0 = bd[c], b1 = bd[c+1];
    for (int r=0; r<512; ++r){
        const float* xr = sx + r*32;
        float a0 = b0, a1 = b1;
        #pragma unroll
        for (int d=0; d<32; ++d){
            float xv = xr[d];
            a0 = fmaf(xv, w0[d], a0);
            a1 = fmaf(xv, w1[d], a1);
        }
        *reinterpret_cast<float2*>(&out[(size_t)(r0+r)*VOCAB_ + c]) = make_float2(a0, a1);
    }
}

// ================= launch =================
extern "C" void kernel_launch(void* const* d_in, const int* in_sizes, int n_in,
                              void* d_out, int out_size, void* d_ws, size_t ws_size,
                              hipStream_t stream)
{
    const float* x   = (const float*)d_in[0];
    const float* Wx1 = (const float*)d_in[1];
    const float* Wh1 = (const float*)d_in[2];
    const float* b1  = (const float*)d_in[3];
    const float* Wx2 = (const float*)d_in[4];
    const float* Wh2 = (const float*)d_in[5];
    const float* b2  = (const float*)d_in[6];
    const float* Wq  = (const float*)d_in[7];
    const float* bq  = (const float*)d_in[8];
    const float* Wk  = (const float*)d_in[9];
    const float* bk  = (const float*)d_in[10];
    const float* Wv  = (const float*)d_in[11];
    const float* bv  = (const float*)d_in[12];
    const float* Wo  = (const float*)d_in[13];
    const float* bo  = (const float*)d_in[14];
    const float* g1  = (const float*)d_in[15];
    const float* be1 = (const float*)d_in[16];
    const float* W1  = (const float*)d_in[17];
    const float* bf1 = (const float*)d_in[18];
    const float* W2  = (const float*)d_in[19];
    const float* bf2 = (const float*)d_in[20];
    const float* g2  = (const float*)d_in[21];
    const float* be2 = (const float*)d_in[22];
    const float* Wd  = (const float*)d_in[23];
    const float* bd  = (const float*)d_in[24];

    const size_t nH = (size_t)B_ * L1_ * 64;    // 1,112,064 elements per state buffer
    float* ws = (float*)d_ws;
    size_t ws_floats = ws_size / sizeof(float);
    float* x3 = ws;                          // 65536 floats
    float* x4 = ws + 65536;                  // 65536 floats
    short* Bp = (short*)(ws + 131072);       // 57344 shorts = 28672 floats
    const size_t base_f = 131072 + 28672;
    const size_t need_f = base_f + nH + 2*nH; // 2 bf16 bufs + 2 f32 bufs
    float* statebase;
    if (ws_floats >= need_f) statebase = ws + base_f;
    else                     statebase = (float*)d_out;    // 262MB scratch, consumed before head writes
    ushort_t* h1a = (ushort_t*)statebase;                  // nH bf16
    ushort_t* h1b = h1a + nH;                              // nH bf16
    float*    c1a = (float*)(h1b + nH);                    // nH f32
    float*    c1b = c1a + nH;                              // nH f32

    hipMemsetAsync(h1a, 0, nH*sizeof(ushort_t), stream);
    hipMemsetAsync(c1a, 0, nH*sizeof(float), stream);

    pack_B1<<<28, 256, 0, stream>>>(Wh1, Wx1, b1, Bp);

    ushort_t *hcur = h1a, *hnxt = h1b;
    float    *ccur = c1a, *cnxt = c1b;
    for (int t=0; t<T1_; t+=4){
        lstm1_step4_mfma<<<dim3(8, B_), 512, 0, stream>>>(x, Bp, hcur, hnxt, ccur, cnxt, t);
        ushort_t* th = hcur; hcur = hnxt; hnxt = th;
        float*    tc = ccur; ccur = cnxt; cnxt = tc;
    }
    lstm2_mfma<<<dim3(B_), 512, 0, stream>>>(hcur, Wh2, Wx2, b2, x3);
    decoder_kernel<<<dim3(B_), 256, 0, stream>>>(x3, Wq,bq,Wk,bk,Wv,bv,Wo,bo,
                                                 g1,be1,W1,bf1,W2,bf2,g2,be2, x4);
    head_kernel<<<dim3(63, 4), 256, 0, stream>>>(x4, Wd, bd, (float*)d_out);
}

// Round 10
// 1019.784 us; speedup vs baseline: 9.8137x; 1.0654x over previous
//
#include <hip/hip_runtime.h>
#include <hip/hip_bf16.h>
#include <math.h>

#define B_  32
#define T1_ 128
#define L1_ 543
#define T2_ 543
#define VOCAB_ 32000

typedef __attribute__((ext_vector_type(8))) short bf16x8;
typedef __attribute__((ext_vector_type(4))) float f32x4;
typedef unsigned short ushort_t;

__device__ __forceinline__ short f2bf(float f){
    union { float f; unsigned u; } v; v.f = f;
    unsigned r = v.u + 0x7FFFu + ((v.u >> 16) & 1u);
    return (short)(r >> 16);
}
// sigmoid: __expf (compiler-generated trans op, hazards handled) + raw v_rcp via
// BUILTIN (not inline asm — rounds 5-8 showed hand-emitted trans asm NaNs).
// rcp is ~1 ulp; feeding bf16 state, Newton step is unnecessary.
__device__ __forceinline__ float fsig(float x){
    return __builtin_amdgcn_rcpf(1.0f + __expf(-x));
}

// ================= prepack Wh1/Wx1/b1 into MFMA B-fragment layout (bf16), UNSCALED =================
__global__ __launch_bounds__(256) void pack_B1(
    const float* __restrict__ Wh1,  // (3,64,256)
    const float* __restrict__ Wx1,  // (3,3,256)
    const float* __restrict__ b1,   // (256)
    short* __restrict__ Bp)         // 7*16*64*8 shorts
{
    int id = blockIdx.x*256 + threadIdx.x;
    if (id >= 7*16*64) return;
    int kt  = id >> 10;
    int rem = id & 1023;
    int nt  = rem >> 6;
    int lane= rem & 63;
    int j = nt*16 + (lane & 15);
    int g = lane >> 4;
    bf16x8 o;
    #pragma unroll
    for (int i=0;i<8;++i){
        int kl = 8*g + i;
        float v = 0.f;
        if (kt < 6){
            int tap = kt >> 1, ch = (kt & 1)*32 + kl;
            v = Wh1[(tap*64 + ch)*256 + j];
        } else {
            if (kl < 9){ int tap = kl/3, ch = kl - 3*tap; v = Wx1[(tap*3 + ch)*256 + j]; }
            else if (kl == 9) v = b1[j];
        }
        o[i] = f2bf(v);
    }
    *(bf16x8*)(Bp + (size_t)id*8) = o;
}

// ================= Stage 1: ConvLSTM1D #1, MFMA, FOUR timesteps per launch (round-9 PASS structure) =================
// grid (8, 32), block 512 (8 waves). Chunk = 68 interior rows, halo 4.
// FIXED row<->l mapping: row r <-> l = l0-4+r. m-index u reads rows u..u+2, stores at row u+1.
// Valid trapezoid at sub-step s: rows [1+s, 75-s); s=3 -> [4,72) = exact interior.
__global__ __launch_bounds__(512) void lstm1_step4_mfma(
    const float* __restrict__ x,       // (B,128,543,3) fp32
    const short* __restrict__ Bp,      // packed B frags
    const ushort_t* __restrict__ h_in, // (B,543,64) bf16 = h(t-1)
    ushort_t* __restrict__ h_out,      // (B,543,64) bf16 = h(t+3)
    const float* __restrict__ c_in,    // (B,543,64) fp32 = c(t-1)
    float* __restrict__ c_out,         // (B,543,64) fp32 = c(t+3)
    int t)
{
    __shared__ short h0s[82*72];       // 82 rows so tile-5 A-reads (rows<=81) stay in-buffer
    __shared__ short h1s[82*72];
    __shared__ short xs4[4*82*4];      // x(t..t+3), rows [0,82), 3ch+pad

    const int tid = threadIdx.x;
    const int wave = tid>>6, lane = tid&63, g = lane>>4, ln = lane&15;
    const int cq = wave&3, mgrp = wave>>2;
    const int b = blockIdx.y, l0 = blockIdx.x*68;
    const int ch = 16*cq + ln;
    const int NT = mgrp ? 2 : 3;
    const int mt0 = mgrp*3;

    // c(t-1) -> registers (long-latency, issue first). Row = m-index + 1.
    float cr[3][4];
    #pragma unroll
    for (int ti=0; ti<3; ++ti)
      #pragma unroll
      for (int rr=0; rr<4; ++rr){
        cr[ti][rr] = 0.f;
        if (ti < NT){
            int row = (mt0+ti)*16 + 4*g + rr + 1;
            int l = l0 - 4 + row;
            if (row < 75 && l >= 0 && l < L1_)
                cr[ti][rr] = c_in[((size_t)b*L1_ + l)*64 + ch];
        }
      }

    // B fragments (shared by all 4 sub-steps)
    bf16x8 Bf[7][4];
    #pragma unroll
    for (int kt=0; kt<7; ++kt)
      #pragma unroll
      for (int gt=0; gt<4; ++gt)
        Bf[kt][gt] = *(const bf16x8*)(Bp + (size_t)(((kt*16 + (gt*4 + cq))*64) + lane)*8);

    // stage h(t-1) rows [0,76) -> h0s; zero h0s rows [76,82); zero ALL h1s
    const ushort_t* hb = h_in + (size_t)b*(L1_*64);
    for (int u=tid; u<76*8; u+=512){
        int row = u>>3, c8 = u&7;
        int l = l0 - 4 + row;
        uint4 v = make_uint4(0u,0u,0u,0u);
        if (l >= 0 && l < L1_) v = *(const uint4*)(hb + (size_t)l*64 + c8*8);
        *(uint4*)(h0s + row*72 + c8*8) = v;
    }
    for (int u=tid; u<216;  u+=512) ((int*)(h0s + 76*72))[u] = 0;
    for (int u=tid; u<2952; u+=512) ((int*)h1s)[u] = 0;
    // stage x(t..t+3), rows [0,82)
    const float* xb0 = x + ((size_t)b*T1_ + t)*(L1_*3);
    for (int u=tid; u<4*82*3; u+=512){
        int st = u/(82*3), rem = u - st*(82*3);
        int row = rem/3, c = rem - 3*row;
        int l = l0 - 4 + row;
        xs4[st*328 + row*4 + c] = f2bf((l>=0 && l<L1_) ? xb0[(size_t)st*(L1_*3) + l*3 + c] : 0.f);
    }
    __syncthreads();

    f32x4 zero4 = {0.f,0.f,0.f,0.f};
    for (int s=0; s<4; ++s){
        const short* src = (s&1) ? h1s : h0s;
        short*       dst = (s&1) ? h0s : h1s;
        const short* xv  = xs4 + s*328;

        f32x4 acc[3][4];
        #pragma unroll
        for (int ti=0; ti<3; ++ti)
          #pragma unroll
          for (int gt=0; gt<4; ++gt) acc[ti][gt] = zero4;

        #pragma unroll
        for (int ti=0; ti<3; ++ti) if (ti < NT){
            const int rbase = (mt0+ti)*16 + ln;
            #pragma unroll
            for (int kt=0; kt<6; ++kt){
                int tap = kt >> 1;
                bf16x8 a = *(const bf16x8*)(src + (rbase + tap)*72 + (kt&1)*32 + 8*g);
                #pragma unroll
                for (int gt=0; gt<4; ++gt)
                    acc[ti][gt] = __builtin_amdgcn_mfma_f32_16x16x32_bf16(a, Bf[kt][gt], acc[ti][gt], 0,0,0);
            }
            bf16x8 a6;
            #pragma unroll
            for (int i=0;i<8;++i) a6[i] = 0;
            if (g == 0){
                #pragma unroll
                for (int i=0;i<8;++i){ int tap = i/3, c = i - 3*tap; a6[i] = xv[(rbase+tap)*4 + c]; }
            } else if (g == 1){
                a6[0] = xv[(rbase+2)*4 + 2];
                a6[1] = (short)0x3F80;
            }
            #pragma unroll
            for (int gt=0; gt<4; ++gt)
                acc[ti][gt] = __builtin_amdgcn_mfma_f32_16x16x32_bf16(a6, Bf[6][gt], acc[ti][gt], 0,0,0);
        }

        // gates: m-index u stored at row u+1; valid rows [1+s, 75-s), l in [0,543)
        #pragma unroll
        for (int ti=0; ti<3; ++ti) if (ti < NT)
          #pragma unroll
          for (int rr=0; rr<4; ++rr){
            int row = (mt0+ti)*16 + 4*g + rr + 1;
            int l = l0 - 4 + row;
            if (row >= 1+s && row < 75-s && l >= 0 && l < L1_){
                float iv = fsig(acc[ti][0][rr]);
                float fv = fsig(acc[ti][1][rr]);
                float gv = fmaxf(acc[ti][2][rr], 0.f);
                float ov = fsig(acc[ti][3][rr]);
                float cv = fv*cr[ti][rr] + iv*gv;
                cr[ti][rr] = cv;
                float hv = ov * fmaxf(cv, 0.f);
                if (s < 3){
                    dst[row*72 + ch] = f2bf(hv);
                } else {
                    size_t idx = ((size_t)b*L1_ + l)*64 + ch;
                    c_out[idx] = cv;
                    h_out[idx] = (ushort_t)f2bf(hv);
                }
            }
          }
        if (s < 3) __syncthreads();
    }
}

// ================= Stage 2: ConvLSTM1D #2, MFMA, persistent, double-buffered (1 barrier/step) =================
// Hazard audit: write xs2[nxt]/hs[nxt] in iter t vs their reads as 'cur' in iter t+1:
// separated by the end-of-t barrier. Reads of xs2[nxt] as 'cur' in iter t-1 completed
// before the end-of-(t-1) barrier, which precedes iter-t writes. hs rows 0/65 (halo)
// zero-initialized in BOTH buffers, never written. Init: single writer per LDS word.
// wave: s = wave&3 (row strip), q = wave>>2 (ch half). gate gi at N-tile nt=2*gi+q.
__global__ __launch_bounds__(512) void lstm2_mfma(
    const ushort_t* __restrict__ x2, // (B,543,64) bf16
    const float* __restrict__ Wh2,   // (3,32,128)
    const float* __restrict__ Wx2,   // (3,1,128)
    const float* __restrict__ b2,    // (128)
    float* __restrict__ out)         // (B,64,32)
{
    __shared__ short hs[2][66*40];
    __shared__ short xs2[2][66];
    const int tid = threadIdx.x;
    const int wave = tid>>6, lane = tid&63, g = lane>>4, ln = lane&15;
    const int s = wave&3, q = wave>>2;
    const int b = blockIdx.x;

    bf16x8 Bf[4][4];
    #pragma unroll
    for (int gi=0; gi<4; ++gi){
        int j = (2*gi + q)*16 + ln;
        #pragma unroll
        for (int kt=0; kt<3; ++kt){
            bf16x8 o;
            #pragma unroll
            for (int i=0;i<8;++i) o[i] = f2bf(Wh2[(kt*32 + 8*g + i)*128 + j]);
            Bf[kt][gi] = o;
        }
        bf16x8 o;
        #pragma unroll
        for (int i=0;i<8;++i) o[i] = 0;
        if (g==0){
            o[0]=f2bf(Wx2[0*128+j]); o[1]=f2bf(Wx2[1*128+j]); o[2]=f2bf(Wx2[2*128+j]);
            o[3]=f2bf(b2[j]);
        }
        Bf[3][gi] = o;
    }

    const ushort_t* xb = x2 + (size_t)b*(T2_*64);

    for (int i=tid; i<2640; i+=512) ((int*)hs)[i] = 0;       // both h buffers (incl. halo rows)
    // x buffers: single writer per word (no race): xs2[0] = x(0) with zero halo; xs2[1] zeroed
    if (tid < 66){
        xs2[1][tid] = 0;
        short v = 0;
        if (tid >= 1 && tid < 65) v = (short)xb[tid - 1];
        xs2[0][tid] = v;
    }
    float creg[4];
    #pragma unroll
    for (int i=0;i<4;++i) creg[i]=0.f;

    ushort_t xreg = (tid < 64) ? xb[64 + tid] : (ushort_t)0; // prefetch x(1)
    __syncthreads();

    const int lA = 16*s + ln;
    const int chn = 16*q + ln;

    for (int t=0; t<T2_; ++t){
        const int cur = t & 1, nxt = cur ^ 1;
        if (tid < 64 && t+1 < T2_) xs2[nxt][1+tid] = (short)xreg;      // x(t+1) -> nxt
        if (tid < 64 && t+2 < T2_) xreg = xb[(size_t)(t+2)*64 + tid];  // prefetch x(t+2)

        f32x4 acc[4];
        f32x4 zero4 = {0.f,0.f,0.f,0.f};
        #pragma unroll
        for (int gi=0; gi<4; ++gi) acc[gi] = zero4;

        #pragma unroll
        for (int kt=0; kt<3; ++kt){
            bf16x8 a = *(const bf16x8*)(&hs[cur][0] + (lA + kt)*40 + 8*g);
            #pragma unroll
            for (int gi=0; gi<4; ++gi)
                acc[gi] = __builtin_amdgcn_mfma_f32_16x16x32_bf16(a, Bf[kt][gi], acc[gi], 0,0,0);
        }
        {
            bf16x8 a3;
            #pragma unroll
            for (int i=0;i<8;++i) a3[i] = 0;
            if (g==0){
                a3[0]=xs2[cur][lA]; a3[1]=xs2[cur][lA+1]; a3[2]=xs2[cur][lA+2];
                a3[3]=(short)0x3F80;
            }
            #pragma unroll
            for (int gi=0; gi<4; ++gi)
                acc[gi] = __builtin_amdgcn_mfma_f32_16x16x32_bf16(a3, Bf[3][gi], acc[gi], 0,0,0);
        }

        #pragma unroll
        for (int r=0; r<4; ++r){
            int l = 16*s + 4*g + r;
            float iv = fsig(acc[0][r]);
            float fv = fsig(acc[1][r]);
            float gv = fmaxf(acc[2][r], 0.f);
            float ov = fsig(acc[3][r]);
            float cv = fv*creg[r] + iv*gv;
            creg[r] = cv;
            float hv = ov * fmaxf(cv, 0.f);
            hs[nxt][(1+l)*40 + chn] = f2bf(hv);
            if (t == T2_-1) out[(size_t)b*2048 + l*32 + chn] = hv;
        }
        __syncthreads();   // nxt writes visible; cur free for overwrite next iter
    }
}

// ================= Transformer decoder, 1 WG per batch =================
__global__ __launch_bounds__(256) void decoder_kernel(
    const float* __restrict__ xin,
    const float* __restrict__ Wq, const float* __restrict__ bq,
    const float* __restrict__ Wk, const float* __restrict__ bk,
    const float* __restrict__ Wv, const float* __restrict__ bv,
    const float* __restrict__ Wo, const float* __restrict__ bo,
    const float* __restrict__ g1, const float* __restrict__ be1,
    const float* __restrict__ W1, const float* __restrict__ bf1,
    const float* __restrict__ W2, const float* __restrict__ bf2,
    const float* __restrict__ g2, const float* __restrict__ be2,
    float* __restrict__ xout)
{
    __shared__ float smem[16384];
    float* sx  = smem;
    float* sq  = smem + 2048;
    float* sk  = smem + 4096;
    float* sv  = smem + 6144;
    float* so  = smem + 8192;
    float* sy  = smem + 10240;
    float* sff = smem + 12288;

    const int b = blockIdx.x;
    const int tid = threadIdx.x;

    for (int i=tid; i<2048; i+=256) sx[i] = xin[(size_t)b*2048 + i];
    __syncthreads();

    for (int i=tid; i<2048; i+=256){
        int s = i >> 5, j = i & 31;
        float aq = bq[j], ak = bk[j], av = bv[j];
        for (int d=0; d<32; ++d){
            float xv = sx[s*32+d];
            aq = fmaf(xv, Wq[d*32+j], aq);
            ak = fmaf(xv, Wk[d*32+j], ak);
            av = fmaf(xv, Wv[d*32+j], av);
        }
        sq[i]=aq; sk[i]=ak; sv[i]=av;
    }
    __syncthreads();

    if (tid < 128){
        int h = tid >> 6, si = tid & 63;
        const int o = h*16;
        float qv[16];
        #pragma unroll
        for (int kk=0; kk<16; ++kk) qv[kk] = sq[si*32 + o + kk];
        float mx = -1e30f;
        for (int ti=0; ti<=si; ++ti){
            float sc = 0.f;
            #pragma unroll
            for (int kk=0; kk<16; ++kk) sc = fmaf(qv[kk], sk[ti*32+o+kk], sc);
            mx = fmaxf(mx, sc*0.25f);
        }
        float sum = 0.f;
        float accv[16];
        #pragma unroll
        for (int kk=0; kk<16; ++kk) accv[kk]=0.f;
        for (int ti=0; ti<=si; ++ti){
            float sc = 0.f;
            #pragma unroll
            for (int kk=0; kk<16; ++kk) sc = fmaf(qv[kk], sk[ti*32+o+kk], sc);
            float p = expf(sc*0.25f - mx);
            sum += p;
            #pragma unroll
            for (int kk=0; kk<16; ++kk) accv[kk] = fmaf(p, sv[ti*32+o+kk], accv[kk]);
        }
        float inv = 1.f/sum;
        #pragma unroll
        for (int kk=0; kk<16; ++kk) so[si*32 + o + kk] = accv[kk]*inv;
    }
    __syncthreads();

    for (int i=tid; i<2048; i+=256){
        int s = i>>5, d = i&31;
        float a = bo[d];
        for (int j=0; j<32; ++j) a = fmaf(so[s*32+j], Wo[j*32+d], a);
        sy[i] = sx[i] + a;
    }
    __syncthreads();
    if (tid < 64){
        float mu=0.f;
        for (int d=0; d<32; ++d) mu += sy[tid*32+d];
        mu *= (1.f/32.f);
        float var=0.f;
        for (int d=0; d<32; ++d){ float dd = sy[tid*32+d]-mu; var = fmaf(dd,dd,var); }
        var *= (1.f/32.f);
        float rs = rsqrtf(var + 1e-5f);
        for (int d=0; d<32; ++d) sy[tid*32+d] = (sy[tid*32+d]-mu)*rs*g1[d] + be1[d];
    }
    __syncthreads();
    for (int i=tid; i<4096; i+=256){
        int s = i>>6, ff = i&63;
        float a = bf1[ff];
        for (int d=0; d<32; ++d) a = fmaf(sy[s*32+d], W1[d*64+ff], a);
        sff[i] = fmaxf(a, 0.f);
    }
    __syncthreads();
    for (int i=tid; i<2048; i+=256){
        int s=i>>5, d=i&31;
        float a = bf2[d];
        for (int ff=0; ff<64; ++ff) a = fmaf(sff[s*64+ff], W2[ff*32+d], a);
        sx[i] = sy[i] + a;
    }
    __syncthreads();
    if (tid < 64){
        float mu=0.f;
        for (int d=0; d<32; ++d) mu += sx[tid*32+d];
        mu *= (1.f/32.f);
        float var=0.f;
        for (int d=0; d<32; ++d){ float dd = sx[tid*32+d]-mu; var = fmaf(dd,dd,var); }
        var *= (1.f/32.f);
        float rs = rsqrtf(var + 1e-5f);
        for (int d=0; d<32; ++d)
            xout[(size_t)b*2048 + tid*32 + d] = (sx[tid*32+d]-mu)*rs*g2[d] + be2[d];
    }
}

// ================= Vocab head: 512-row x 512-col tiles, Wd cols in registers =================
__global__ __launch_bounds__(256) void head_kernel(
    const float* __restrict__ xin,  // (2048, 32)
    const float* __restrict__ Wd,   // (32, 32000)
    const float* __restrict__ bd,   // (32000)
    float* __restrict__ out)        // (2048, 32000)
{
    __shared__ float sx[512*32];    // 64 KB
    const int r0 = blockIdx.y * 512;
    const int c0 = blockIdx.x * 512;
    const int tid = threadIdx.x;
    for (int u=tid; u<512*8; u+=256){
        int row = u>>3, c8 = u&7;
        *(float4*)(sx + row*32 + c8*4) = *(const float4*)(xin + (size_t)(r0+row)*32 + c8*4);
    }
    __syncthreads();
    int c = c0 + tid*2;
    if (c >= VOCAB_) return;
    float w0[32], w1[32];
    #pragma unroll
    for (int d=0; d<32; ++d){
        w0[d] = Wd[(size_t)d*VOCAB_ + c];
        w1[d] = Wd[(size_t)d*VOCAB_ + c + 1];
    }
    float b0 = bd[c], b1 = bd[c+1];
    for (int r=0; r<512; ++r){
        const float* xr = sx + r*32;
        float a0 = b0, a1 = b1;
        #pragma unroll
        for (int d=0; d<32; ++d){
            float xv = xr[d];
            a0 = fmaf(xv, w0[d], a0);
            a1 = fmaf(xv, w1[d], a1);
        }
        *reinterpret_cast<float2*>(&out[(size_t)(r0+r)*VOCAB_ + c]) = make_float2(a0, a1);
    }
}

// ================= launch =================
extern "C" void kernel_launch(void* const* d_in, const int* in_sizes, int n_in,
                              void* d_out, int out_size, void* d_ws, size_t ws_size,
                              hipStream_t stream)
{
    const float* x   = (const float*)d_in[0];
    const float* Wx1 = (const float*)d_in[1];
    const float* Wh1 = (const float*)d_in[2];
    const float* b1  = (const float*)d_in[3];
    const float* Wx2 = (const float*)d_in[4];
    const float* Wh2 = (const float*)d_in[5];
    const float* b2  = (const float*)d_in[6];
    const float* Wq  = (const float*)d_in[7];
    const float* bq  = (const float*)d_in[8];
    const float* Wk  = (const float*)d_in[9];
    const float* bk  = (const float*)d_in[10];
    const float* Wv  = (const float*)d_in[11];
    const float* bv  = (const float*)d_in[12];
    const float* Wo  = (const float*)d_in[13];
    const float* bo  = (const float*)d_in[14];
    const float* g1  = (const float*)d_in[15];
    const float* be1 = (const float*)d_in[16];
    const float* W1  = (const float*)d_in[17];
    const float* bf1 = (const float*)d_in[18];
    const float* W2  = (const float*)d_in[19];
    const float* bf2 = (const float*)d_in[20];
    const float* g2  = (const float*)d_in[21];
    const float* be2 = (const float*)d_in[22];
    const float* Wd  = (const float*)d_in[23];
    const float* bd  = (const float*)d_in[24];

    const size_t nH = (size_t)B_ * L1_ * 64;    // 1,112,064 elements per state buffer
    float* ws = (float*)d_ws;
    size_t ws_floats = ws_size / sizeof(float);
    float* x3 = ws;                          // 65536 floats
    float* x4 = ws + 65536;                  // 65536 floats
    short* Bp = (short*)(ws + 131072);       // 57344 shorts = 28672 floats
    const size_t base_f = 131072 + 28672;
    const size_t need_f = base_f + nH + 2*nH; // 2 bf16 bufs + 2 f32 bufs
    float* statebase;
    if (ws_floats >= need_f) statebase = ws + base_f;
    else                     statebase = (float*)d_out;    // 262MB scratch, consumed before head writes
    ushort_t* h1a = (ushort_t*)statebase;                  // nH bf16
    ushort_t* h1b = h1a + nH;                              // nH bf16
    float*    c1a = (float*)(h1b + nH);                    // nH f32
    float*    c1b = c1a + nH;                              // nH f32

    hipMemsetAsync(h1a, 0, nH*sizeof(ushort_t), stream);
    hipMemsetAsync(c1a, 0, nH*sizeof(float), stream);

    pack_B1<<<28, 256, 0, stream>>>(Wh1, Wx1, b1, Bp);

    ushort_t *hcur = h1a, *hnxt = h1b;
    float    *ccur = c1a, *cnxt = c1b;
    for (int t=0; t<T1_; t+=4){
        lstm1_step4_mfma<<<dim3(8, B_), 512, 0, stream>>>(x, Bp, hcur, hnxt, ccur, cnxt, t);
        ushort_t* th = hcur; hcur = hnxt; hnxt = th;
        float*    tc = ccur; ccur = cnxt; cnxt = tc;
    }
    lstm2_mfma<<<dim3(B_), 512, 0, stream>>>(hcur, Wh2, Wx2, b2, x3);
    decoder_kernel<<<dim3(B_), 256, 0, stream>>>(x3, Wq,bq,Wk,bk,Wv,bv,Wo,bo,
                                                 g1,be1,W1,bf1,W2,bf2,g2,be2, x4);
    head_kernel<<<dim3(63, 4), 256, 0, stream>>>(x4, Wd, bd, (float*)d_out);
}

// Round 11
// 972.905 us; speedup vs baseline: 10.2865x; 1.0482x over previous
//
#include <hip/hip_runtime.h>
#include <hip/hip_bf16.h>
#include <math.h>

#define B_  32
#define T1_ 128
#define L1_ 543
#define T2_ 543
#define VOCAB_ 32000

typedef __attribute__((ext_vector_type(8))) short bf16x8;
typedef __attribute__((ext_vector_type(4))) float f32x4;
typedef unsigned short ushort_t;

__device__ __forceinline__ short f2bf(float f){
    union { float f; unsigned u; } v; v.f = f;
    unsigned r = v.u + 0x7FFFu + ((v.u >> 16) & 1u);
    return (short)(r >> 16);
}
// sigmoid: __expf (compiler-generated trans op, hazards handled) + rcp BUILTIN
// (not inline asm — rounds 5-8 showed hand-emitted trans asm NaNs).
__device__ __forceinline__ float fsig(float x){
    return __builtin_amdgcn_rcpf(1.0f + __expf(-x));
}

// ================= prepack Wh1/Wx1/b1 into MFMA B-fragment layout (bf16), UNSCALED =================
__global__ __launch_bounds__(256) void pack_B1(
    const float* __restrict__ Wh1,  // (3,64,256)
    const float* __restrict__ Wx1,  // (3,3,256)
    const float* __restrict__ b1,   // (256)
    short* __restrict__ Bp)         // 7*16*64*8 shorts
{
    int id = blockIdx.x*256 + threadIdx.x;
    if (id >= 7*16*64) return;
    int kt  = id >> 10;
    int rem = id & 1023;
    int nt  = rem >> 6;
    int lane= rem & 63;
    int j = nt*16 + (lane & 15);
    int g = lane >> 4;
    bf16x8 o;
    #pragma unroll
    for (int i=0;i<8;++i){
        int kl = 8*g + i;
        float v = 0.f;
        if (kt < 6){
            int tap = kt >> 1, ch = (kt & 1)*32 + kl;
            v = Wh1[(tap*64 + ch)*256 + j];
        } else {
            if (kl < 9){ int tap = kl/3, ch = kl - 3*tap; v = Wx1[(tap*3 + ch)*256 + j]; }
            else if (kl == 9) v = b1[j];
        }
        o[i] = f2bf(v);
    }
    *(bf16x8*)(Bp + (size_t)id*8) = o;
}

// ================= Stage 1: ConvLSTM1D #1, MFMA, EIGHT timesteps per launch =================
// grid (8, 32), block 512 (8 waves). Chunk = 68 interior rows, halo 8.
// FIXED row<->l mapping: row r <-> l = l0-8+r. m-index u reads rows u..u+2, stores at row u+1
// (same convention verified in the 4-step round-9/10 PASS kernels).
// Valid trapezoid at sub-step s: rows [1+s, 83-s); s=7 -> [8,76) = exact interior.
// 6 M-tiles (m 0..95), waves split {0,1,2}/{3,4,5} — balanced NT=3 for all waves.
// Masked-tile A/x overreads reach row <= 97 -> buffers sized 98 rows; garbage rows feed
// only discarded D-rows (MFMA row i of D depends only on row i of A).
__global__ __launch_bounds__(512) void lstm1_step8_mfma(
    const float* __restrict__ x,       // (B,128,543,3) fp32
    const short* __restrict__ Bp,      // packed B frags
    const ushort_t* __restrict__ h_in, // (B,543,64) bf16 = h(t-1)
    ushort_t* __restrict__ h_out,      // (B,543,64) bf16 = h(t+7)
    const float* __restrict__ c_in,    // (B,543,64) fp32 = c(t-1)
    float* __restrict__ c_out,         // (B,543,64) fp32 = c(t+7)
    int t)
{
    __shared__ short h0s[98*72];       // 14112 B
    __shared__ short h1s[98*72];
    __shared__ short xs8[8*98*4];      // x(t..t+7), rows [0,98), 3ch+pad; 6272 B

    const int tid = threadIdx.x;
    const int wave = tid>>6, lane = tid&63, g = lane>>4, ln = lane&15;
    const int cq = wave&3, mgrp = wave>>2;
    const int b = blockIdx.y, l0 = blockIdx.x*68;
    const int ch = 16*cq + ln;
    const int mt0 = mgrp*3;            // tiles {0,1,2} or {3,4,5}

    // c(t-1) -> registers. Row = m-index + 1; valid rows [1,83).
    float cr[3][4];
    #pragma unroll
    for (int ti=0; ti<3; ++ti)
      #pragma unroll
      for (int rr=0; rr<4; ++rr){
        cr[ti][rr] = 0.f;
        int row = (mt0+ti)*16 + 4*g + rr + 1;
        int l = l0 - 8 + row;
        if (row < 83 && l >= 0 && l < L1_)
            cr[ti][rr] = c_in[((size_t)b*L1_ + l)*64 + ch];
      }

    // B fragments (shared by all 8 sub-steps)
    bf16x8 Bf[7][4];
    #pragma unroll
    for (int kt=0; kt<7; ++kt)
      #pragma unroll
      for (int gt=0; gt<4; ++gt)
        Bf[kt][gt] = *(const bf16x8*)(Bp + (size_t)(((kt*16 + (gt*4 + cq))*64) + lane)*8);

    // stage h(t-1) rows [0,84) -> h0s; zero h0s rows [84,98); zero ALL h1s
    const ushort_t* hb = h_in + (size_t)b*(L1_*64);
    for (int u=tid; u<84*8; u+=512){
        int row = u>>3, c8 = u&7;
        int l = l0 - 8 + row;
        uint4 v = make_uint4(0u,0u,0u,0u);
        if (l >= 0 && l < L1_) v = *(const uint4*)(hb + (size_t)l*64 + c8*8);
        *(uint4*)(h0s + row*72 + c8*8) = v;
    }
    for (int u=tid; u<504;  u+=512) ((int*)(h0s + 84*72))[u] = 0;   // rows [84,98)
    for (int u=tid; u<3528; u+=512) ((int*)h1s)[u] = 0;             // all 98 rows
    // stage x(t..t+7), all rows [0,98) with l-mask (rows>=84 feed only discarded tiles)
    const float* xb0 = x + ((size_t)b*T1_ + t)*(L1_*3);
    for (int u=tid; u<8*98*3; u+=512){
        int st = u/(98*3), rem = u - st*(98*3);
        int row = rem/3, c = rem - 3*row;
        int l = l0 - 8 + row;
        xs8[st*392 + row*4 + c] = f2bf((l>=0 && l<L1_) ? xb0[(size_t)st*(L1_*3) + l*3 + c] : 0.f);
    }
    __syncthreads();

    f32x4 zero4 = {0.f,0.f,0.f,0.f};
    for (int s=0; s<8; ++s){
        const short* src = (s&1) ? h1s : h0s;
        short*       dst = (s&1) ? h0s : h1s;
        const short* xv  = xs8 + s*392;

        f32x4 acc[3][4];
        #pragma unroll
        for (int ti=0; ti<3; ++ti)
          #pragma unroll
          for (int gt=0; gt<4; ++gt) acc[ti][gt] = zero4;

        #pragma unroll
        for (int ti=0; ti<3; ++ti){
            const int rbase = (mt0+ti)*16 + ln;
            #pragma unroll
            for (int kt=0; kt<6; ++kt){
                int tap = kt >> 1;
                bf16x8 a = *(const bf16x8*)(src + (rbase + tap)*72 + (kt&1)*32 + 8*g);
                #pragma unroll
                for (int gt=0; gt<4; ++gt)
                    acc[ti][gt] = __builtin_amdgcn_mfma_f32_16x16x32_bf16(a, Bf[kt][gt], acc[ti][gt], 0,0,0);
            }
            bf16x8 a6;
            #pragma unroll
            for (int i=0;i<8;++i) a6[i] = 0;
            if (g == 0){
                #pragma unroll
                for (int i=0;i<8;++i){ int tap = i/3, c = i - 3*tap; a6[i] = xv[(rbase+tap)*4 + c]; }
            } else if (g == 1){
                a6[0] = xv[(rbase+2)*4 + 2];
                a6[1] = (short)0x3F80;
            }
            #pragma unroll
            for (int gt=0; gt<4; ++gt)
                acc[ti][gt] = __builtin_amdgcn_mfma_f32_16x16x32_bf16(a6, Bf[6][gt], acc[ti][gt], 0,0,0);
        }

        // gates: m-index u stored at row u+1; valid rows [1+s, 83-s), l in [0,543)
        #pragma unroll
        for (int ti=0; ti<3; ++ti)
          #pragma unroll
          for (int rr=0; rr<4; ++rr){
            int row = (mt0+ti)*16 + 4*g + rr + 1;
            int l = l0 - 8 + row;
            if (row >= 1+s && row < 83-s && l >= 0 && l < L1_){
                float iv = fsig(acc[ti][0][rr]);
                float fv = fsig(acc[ti][1][rr]);
                float gv = fmaxf(acc[ti][2][rr], 0.f);
                float ov = fsig(acc[ti][3][rr]);
                float cv = fv*cr[ti][rr] + iv*gv;
                cr[ti][rr] = cv;
                float hv = ov * fmaxf(cv, 0.f);
                if (s < 7){
                    dst[row*72 + ch] = f2bf(hv);
                } else {
                    size_t idx = ((size_t)b*L1_ + l)*64 + ch;
                    c_out[idx] = cv;
                    h_out[idx] = (ushort_t)f2bf(hv);
                }
            }
          }
        if (s < 7) __syncthreads();
    }
}

// ================= Stage 2: ConvLSTM1D #2, MFMA, persistent, double-buffered (round-10 PASS verbatim) =================
__global__ __launch_bounds__(512) void lstm2_mfma(
    const ushort_t* __restrict__ x2, // (B,543,64) bf16
    const float* __restrict__ Wh2,   // (3,32,128)
    const float* __restrict__ Wx2,   // (3,1,128)
    const float* __restrict__ b2,    // (128)
    float* __restrict__ out)         // (B,64,32)
{
    __shared__ short hs[2][66*40];
    __shared__ short xs2[2][66];
    const int tid = threadIdx.x;
    const int wave = tid>>6, lane = tid&63, g = lane>>4, ln = lane&15;
    const int s = wave&3, q = wave>>2;
    const int b = blockIdx.x;

    bf16x8 Bf[4][4];
    #pragma unroll
    for (int gi=0; gi<4; ++gi){
        int j = (2*gi + q)*16 + ln;
        #pragma unroll
        for (int kt=0; kt<3; ++kt){
            bf16x8 o;
            #pragma unroll
            for (int i=0;i<8;++i) o[i] = f2bf(Wh2[(kt*32 + 8*g + i)*128 + j]);
            Bf[kt][gi] = o;
        }
        bf16x8 o;
        #pragma unroll
        for (int i=0;i<8;++i) o[i] = 0;
        if (g==0){
            o[0]=f2bf(Wx2[0*128+j]); o[1]=f2bf(Wx2[1*128+j]); o[2]=f2bf(Wx2[2*128+j]);
            o[3]=f2bf(b2[j]);
        }
        Bf[3][gi] = o;
    }

    const ushort_t* xb = x2 + (size_t)b*(T2_*64);

    for (int i=tid; i<2640; i+=512) ((int*)hs)[i] = 0;
    if (tid < 66){
        xs2[1][tid] = 0;
        short v = 0;
        if (tid >= 1 && tid < 65) v = (short)xb[tid - 1];
        xs2[0][tid] = v;
    }
    float creg[4];
    #pragma unroll
    for (int i=0;i<4;++i) creg[i]=0.f;

    ushort_t xreg = (tid < 64) ? xb[64 + tid] : (ushort_t)0;
    __syncthreads();

    const int lA = 16*s + ln;
    const int chn = 16*q + ln;

    for (int t=0; t<T2_; ++t){
        const int cur = t & 1, nxt = cur ^ 1;
        if (tid < 64 && t+1 < T2_) xs2[nxt][1+tid] = (short)xreg;
        if (tid < 64 && t+2 < T2_) xreg = xb[(size_t)(t+2)*64 + tid];

        f32x4 acc[4];
        f32x4 zero4 = {0.f,0.f,0.f,0.f};
        #pragma unroll
        for (int gi=0; gi<4; ++gi) acc[gi] = zero4;

        #pragma unroll
        for (int kt=0; kt<3; ++kt){
            bf16x8 a = *(const bf16x8*)(&hs[cur][0] + (lA + kt)*40 + 8*g);
            #pragma unroll
            for (int gi=0; gi<4; ++gi)
                acc[gi] = __builtin_amdgcn_mfma_f32_16x16x32_bf16(a, Bf[kt][gi], acc[gi], 0,0,0);
        }
        {
            bf16x8 a3;
            #pragma unroll
            for (int i=0;i<8;++i) a3[i] = 0;
            if (g==0){
                a3[0]=xs2[cur][lA]; a3[1]=xs2[cur][lA+1]; a3[2]=xs2[cur][lA+2];
                a3[3]=(short)0x3F80;
            }
            #pragma unroll
            for (int gi=0; gi<4; ++gi)
                acc[gi] = __builtin_amdgcn_mfma_f32_16x16x32_bf16(a3, Bf[3][gi], acc[gi], 0,0,0);
        }

        #pragma unroll
        for (int r=0; r<4; ++r){
            int l = 16*s + 4*g + r;
            float iv = fsig(acc[0][r]);
            float fv = fsig(acc[1][r]);
            float gv = fmaxf(acc[2][r], 0.f);
            float ov = fsig(acc[3][r]);
            float cv = fv*creg[r] + iv*gv;
            creg[r] = cv;
            float hv = ov * fmaxf(cv, 0.f);
            hs[nxt][(1+l)*40 + chn] = f2bf(hv);
            if (t == T2_-1) out[(size_t)b*2048 + l*32 + chn] = hv;
        }
        __syncthreads();
    }
}

// ================= Transformer decoder, 1 WG per batch =================
__global__ __launch_bounds__(256) void decoder_kernel(
    const float* __restrict__ xin,
    const float* __restrict__ Wq, const float* __restrict__ bq,
    const float* __restrict__ Wk, const float* __restrict__ bk,
    const float* __restrict__ Wv, const float* __restrict__ bv,
    const float* __restrict__ Wo, const float* __restrict__ bo,
    const float* __restrict__ g1, const float* __restrict__ be1,
    const float* __restrict__ W1, const float* __restrict__ bf1,
    const float* __restrict__ W2, const float* __restrict__ bf2,
    const float* __restrict__ g2, const float* __restrict__ be2,
    float* __restrict__ xout)
{
    __shared__ float smem[16384];
    float* sx  = smem;
    float* sq  = smem + 2048;
    float* sk  = smem + 4096;
    float* sv  = smem + 6144;
    float* so  = smem + 8192;
    float* sy  = smem + 10240;
    float* sff = smem + 12288;

    const int b = blockIdx.x;
    const int tid = threadIdx.x;

    for (int i=tid; i<2048; i+=256) sx[i] = xin[(size_t)b*2048 + i];
    __syncthreads();

    for (int i=tid; i<2048; i+=256){
        int s = i >> 5, j = i & 31;
        float aq = bq[j], ak = bk[j], av = bv[j];
        for (int d=0; d<32; ++d){
            float xv = sx[s*32+d];
            aq = fmaf(xv, Wq[d*32+j], aq);
            ak = fmaf(xv, Wk[d*32+j], ak);
            av = fmaf(xv, Wv[d*32+j], av);
        }
        sq[i]=aq; sk[i]=ak; sv[i]=av;
    }
    __syncthreads();

    if (tid < 128){
        int h = tid >> 6, si = tid & 63;
        const int o = h*16;
        float qv[16];
        #pragma unroll
        for (int kk=0; kk<16; ++kk) qv[kk] = sq[si*32 + o + kk];
        float mx = -1e30f;
        for (int ti=0; ti<=si; ++ti){
            float sc = 0.f;
            #pragma unroll
            for (int kk=0; kk<16; ++kk) sc = fmaf(qv[kk], sk[ti*32+o+kk], sc);
            mx = fmaxf(mx, sc*0.25f);
        }
        float sum = 0.f;
        float accv[16];
        #pragma unroll
        for (int kk=0; kk<16; ++kk) accv[kk]=0.f;
        for (int ti=0; ti<=si; ++ti){
            float sc = 0.f;
            #pragma unroll
            for (int kk=0; kk<16; ++kk) sc = fmaf(qv[kk], sk[ti*32+o+kk], sc);
            float p = expf(sc*0.25f - mx);
            sum += p;
            #pragma unroll
            for (int kk=0; kk<16; ++kk) accv[kk] = fmaf(p, sv[ti*32+o+kk], accv[kk]);
        }
        float inv = 1.f/sum;
        #pragma unroll
        for (int kk=0; kk<16; ++kk) so[si*32 + o + kk] = accv[kk]*inv;
    }
    __syncthreads();

    for (int i=tid; i<2048; i+=256){
        int s = i>>5, d = i&31;
        float a = bo[d];
        for (int j=0; j<32; ++j) a = fmaf(so[s*32+j], Wo[j*32+d], a);
        sy[i] = sx[i] + a;
    }
    __syncthreads();
    if (tid < 64){
        float mu=0.f;
        for (int d=0; d<32; ++d) mu += sy[tid*32+d];
        mu *= (1.f/32.f);
        float var=0.f;
        for (int d=0; d<32; ++d){ float dd = sy[tid*32+d]-mu; var = fmaf(dd,dd,var); }
        var *= (1.f/32.f);
        float rs = rsqrtf(var + 1e-5f);
        for (int d=0; d<32; ++d) sy[tid*32+d] = (sy[tid*32+d]-mu)*rs*g1[d] + be1[d];
    }
    __syncthreads();
    for (int i=tid; i<4096; i+=256){
        int s = i>>6, ff = i&63;
        float a = bf1[ff];
        for (int d=0; d<32; ++d) a = fmaf(sy[s*32+d], W1[d*64+ff], a);
        sff[i] = fmaxf(a, 0.f);
    }
    __syncthreads();
    for (int i=tid; i<2048; i+=256){
        int s=i>>5, d=i&31;
        float a = bf2[d];
        for (int ff=0; ff<64; ++ff) a = fmaf(sff[s*64+ff], W2[ff*32+d], a);
        sx[i] = sy[i] + a;
    }
    __syncthreads();
    if (tid < 64){
        float mu=0.f;
        for (int d=0; d<32; ++d) mu += sx[tid*32+d];
        mu *= (1.f/32.f);
        float var=0.f;
        for (int d=0; d<32; ++d){ float dd = sx[tid*32+d]-mu; var = fmaf(dd,dd,var); }
        var *= (1.f/32.f);
        float rs = rsqrtf(var + 1e-5f);
        for (int d=0; d<32; ++d)
            xout[(size_t)b*2048 + tid*32 + d] = (sx[tid*32+d]-mu)*rs*g2[d] + be2[d];
    }
}

// ================= Vocab head: 512-row x 512-col tiles, Wd cols in registers =================
__global__ __launch_bounds__(256) void head_kernel(
    const float* __restrict__ xin,  // (2048, 32)
    const float* __restrict__ Wd,   // (32, 32000)
    const float* __restrict__ bd,   // (32000)
    float* __restrict__ out)        // (2048, 32000)
{
    __shared__ float sx[512*32];    // 64 KB
    const int r0 = blockIdx.y * 512;
    const int c0 = blockIdx.x * 512;
    const int tid = threadIdx.x;
    for (int u=tid; u<512*8; u+=256){
        int row = u>>3, c8 = u&7;
        *(float4*)(sx + row*32 + c8*4) = *(const float4*)(xin + (size_t)(r0+row)*32 + c8*4);
    }
    __syncthreads();
    int c = c0 + tid*2;
    if (c >= VOCAB_) return;
    float w0[32], w1[32];
    #pragma unroll
    for (int d=0; d<32; ++d){
        w0[d] = Wd[(size_t)d*VOCAB_ + c];
        w1[d] = Wd[(size_t)d*VOCAB_ + c + 1];
    }
    float b0 = bd[c], b1 = bd[c+1];
    for (int r=0; r<512; ++r){
        const float* xr = sx + r*32;
        float a0 = b0, a1 = b1;
        #pragma unroll
        for (int d=0; d<32; ++d){
            float xv = xr[d];
            a0 = fmaf(xv, w0[d], a0);
            a1 = fmaf(xv, w1[d], a1);
        }
        *reinterpret_cast<float2*>(&out[(size_t)(r0+r)*VOCAB_ + c]) = make_float2(a0, a1);
    }
}

// ================= launch =================
extern "C" void kernel_launch(void* const* d_in, const int* in_sizes, int n_in,
                              void* d_out, int out_size, void* d_ws, size_t ws_size,
                              hipStream_t stream)
{
    const float* x   = (const float*)d_in[0];
    const float* Wx1 = (const float*)d_in[1];
    const float* Wh1 = (const float*)d_in[2];
    const float* b1  = (const float*)d_in[3];
    const float* Wx2 = (const float*)d_in[4];
    const float* Wh2 = (const float*)d_in[5];
    const float* b2  = (const float*)d_in[6];
    const float* Wq  = (const float*)d_in[7];
    const float* bq  = (const float*)d_in[8];
    const float* Wk  = (const float*)d_in[9];
    const float* bk  = (const float*)d_in[10];
    const float* Wv  = (const float*)d_in[11];
    const float* bv  = (const float*)d_in[12];
    const float* Wo  = (const float*)d_in[13];
    const float* bo  = (const float*)d_in[14];
    const float* g1  = (const float*)d_in[15];
    const float* be1 = (const float*)d_in[16];
    const float* W1  = (const float*)d_in[17];
    const float* bf1 = (const float*)d_in[18];
    const float* W2  = (const float*)d_in[19];
    const float* bf2 = (const float*)d_in[20];
    const float* g2  = (const float*)d_in[21];
    const float* be2 = (const float*)d_in[22];
    const float* Wd  = (const float*)d_in[23];
    const float* bd  = (const float*)d_in[24];

    const size_t nH = (size_t)B_ * L1_ * 64;    // 1,112,064 elements per state buffer
    float* ws = (float*)d_ws;
    size_t ws_floats = ws_size / sizeof(float);
    float* x3 = ws;                          // 65536 floats
    float* x4 = ws + 65536;                  // 65536 floats
    short* Bp = (short*)(ws + 131072);       // 57344 shorts = 28672 floats
    const size_t base_f = 131072 + 28672;
    const size_t need_f = base_f + nH + 2*nH; // 2 bf16 bufs + 2 f32 bufs
    float* statebase;
    if (ws_floats >= need_f) statebase = ws + base_f;
    else                     statebase = (float*)d_out;    // 262MB scratch, consumed before head writes
    ushort_t* h1a = (ushort_t*)statebase;                  // nH bf16
    ushort_t* h1b = h1a + nH;                              // nH bf16
    float*    c1a = (float*)(h1b + nH);                    // nH f32
    float*    c1b = c1a + nH;                              // nH f32

    hipMemsetAsync(h1a, 0, nH*sizeof(ushort_t), stream);
    hipMemsetAsync(c1a, 0, nH*sizeof(float), stream);

    pack_B1<<<28, 256, 0, stream>>>(Wh1, Wx1, b1, Bp);

    ushort_t *hcur = h1a, *hnxt = h1b;
    float    *ccur = c1a, *cnxt = c1b;
    for (int t=0; t<T1_; t+=8){
        lstm1_step8_mfma<<<dim3(8, B_), 512, 0, stream>>>(x, Bp, hcur, hnxt, ccur, cnxt, t);
        ushort_t* th = hcur; hcur = hnxt; hnxt = th;
        float*    tc = ccur; ccur = cnxt; cnxt = tc;
    }
    lstm2_mfma<<<dim3(B_), 512, 0, stream>>>(hcur, Wh2, Wx2, b2, x3);
    decoder_kernel<<<dim3(B_), 256, 0, stream>>>(x3, Wq,bq,Wk,bk,Wv,bv,Wo,bo,
                                                 g1,be1,W1,bf1,W2,bf2,g2,be2, x4);
    head_kernel<<<dim3(63, 4), 256, 0, stream>>>(x4, Wd, bd, (float*)d_out);
}

// Round 12
// 968.312 us; speedup vs baseline: 10.3353x; 1.0047x over previous
//
#include <hip/hip_runtime.h>
#include <hip/hip_bf16.h>
#include <math.h>

#define B_  32
#define T1_ 128
#define L1_ 543
#define T2_ 543
#define VOCAB_ 32000

typedef __attribute__((ext_vector_type(8))) short bf16x8;
typedef __attribute__((ext_vector_type(4))) float f32x4;
typedef unsigned short ushort_t;

__device__ __forceinline__ short f2bf(float f){
    union { float f; unsigned u; } v; v.f = f;
    unsigned r = v.u + 0x7FFFu + ((v.u >> 16) & 1u);
    return (short)(r >> 16);
}
// sigmoid: __expf (compiler-generated trans op, hazards handled) + rcp BUILTIN
// (not inline asm — rounds 5-8 showed hand-emitted trans asm NaNs).
__device__ __forceinline__ float fsig(float x){
    return __builtin_amdgcn_rcpf(1.0f + __expf(-x));
}

// ================= prepack Wh1/Wx1/b1 into MFMA B-fragment layout (bf16), UNSCALED =================
__global__ __launch_bounds__(256) void pack_B1(
    const float* __restrict__ Wh1,  // (3,64,256)
    const float* __restrict__ Wx1,  // (3,3,256)
    const float* __restrict__ b1,   // (256)
    short* __restrict__ Bp)         // 7*16*64*8 shorts
{
    int id = blockIdx.x*256 + threadIdx.x;
    if (id >= 7*16*64) return;
    int kt  = id >> 10;
    int rem = id & 1023;
    int nt  = rem >> 6;
    int lane= rem & 63;
    int j = nt*16 + (lane & 15);
    int g = lane >> 4;
    bf16x8 o;
    #pragma unroll
    for (int i=0;i<8;++i){
        int kl = 8*g + i;
        float v = 0.f;
        if (kt < 6){
            int tap = kt >> 1, ch = (kt & 1)*32 + kl;
            v = Wh1[(tap*64 + ch)*256 + j];
        } else {
            if (kl < 9){ int tap = kl/3, ch = kl - 3*tap; v = Wx1[(tap*3 + ch)*256 + j]; }
            else if (kl == 9) v = b1[j];
        }
        o[i] = f2bf(v);
    }
    *(bf16x8*)(Bp + (size_t)id*8) = o;
}

// ================= Stage 1: ConvLSTM1D #1, MFMA, EIGHT timesteps per launch =================
// grid (8, 32), block 512 (8 waves). Chunk = 68 interior rows, halo 8.
// FIXED row<->l mapping: row r <-> l = l0-8+r. m-index u reads rows u..u+2, stores at row u+1.
// Valid trapezoid at sub-step s: rows [1+s, 83-s); s=7 -> [8,76) = exact interior.
// TILE-5 SKIP: valid m-indices [s, 82-s); tile 5 (m 80..95) intersects only for s<2 ->
// skip its 28 MFMAs for s>=2 (gate mask already excludes those rows; acc never read unguarded).
__global__ __launch_bounds__(512) void lstm1_step8_mfma(
    const float* __restrict__ x,       // (B,128,543,3) fp32
    const short* __restrict__ Bp,      // packed B frags
    const ushort_t* __restrict__ h_in, // (B,543,64) bf16 = h(t-1)
    ushort_t* __restrict__ h_out,      // (B,543,64) bf16 = h(t+7)
    const float* __restrict__ c_in,    // (B,543,64) fp32 = c(t-1)
    float* __restrict__ c_out,         // (B,543,64) fp32 = c(t+7)
    int t)
{
    __shared__ short h0s[98*72];
    __shared__ short h1s[98*72];
    __shared__ short xs8[8*98*4];      // x(t..t+7), rows [0,98), 3ch+pad

    const int tid = threadIdx.x;
    const int wave = tid>>6, lane = tid&63, g = lane>>4, ln = lane&15;
    const int cq = wave&3, mgrp = wave>>2;
    const int b = blockIdx.y, l0 = blockIdx.x*68;
    const int ch = 16*cq + ln;
    const int mt0 = mgrp*3;            // tiles {0,1,2} or {3,4,5}

    // c(t-1) -> registers. Row = m-index + 1; valid rows [1,83).
    float cr[3][4];
    #pragma unroll
    for (int ti=0; ti<3; ++ti)
      #pragma unroll
      for (int rr=0; rr<4; ++rr){
        cr[ti][rr] = 0.f;
        int row = (mt0+ti)*16 + 4*g + rr + 1;
        int l = l0 - 8 + row;
        if (row < 83 && l >= 0 && l < L1_)
            cr[ti][rr] = c_in[((size_t)b*L1_ + l)*64 + ch];
      }

    // B fragments (shared by all 8 sub-steps)
    bf16x8 Bf[7][4];
    #pragma unroll
    for (int kt=0; kt<7; ++kt)
      #pragma unroll
      for (int gt=0; gt<4; ++gt)
        Bf[kt][gt] = *(const bf16x8*)(Bp + (size_t)(((kt*16 + (gt*4 + cq))*64) + lane)*8);

    // stage h(t-1) rows [0,84) -> h0s; zero h0s rows [84,98); zero ALL h1s
    const ushort_t* hb = h_in + (size_t)b*(L1_*64);
    for (int u=tid; u<84*8; u+=512){
        int row = u>>3, c8 = u&7;
        int l = l0 - 8 + row;
        uint4 v = make_uint4(0u,0u,0u,0u);
        if (l >= 0 && l < L1_) v = *(const uint4*)(hb + (size_t)l*64 + c8*8);
        *(uint4*)(h0s + row*72 + c8*8) = v;
    }
    for (int u=tid; u<504;  u+=512) ((int*)(h0s + 84*72))[u] = 0;
    for (int u=tid; u<3528; u+=512) ((int*)h1s)[u] = 0;
    // stage x(t..t+7), rows [0,98)
    const float* xb0 = x + ((size_t)b*T1_ + t)*(L1_*3);
    for (int u=tid; u<8*98*3; u+=512){
        int st = u/(98*3), rem = u - st*(98*3);
        int row = rem/3, c = rem - 3*row;
        int l = l0 - 8 + row;
        xs8[st*392 + row*4 + c] = f2bf((l>=0 && l<L1_) ? xb0[(size_t)st*(L1_*3) + l*3 + c] : 0.f);
    }
    __syncthreads();

    f32x4 zero4 = {0.f,0.f,0.f,0.f};
    for (int s=0; s<8; ++s){
        const short* src = (s&1) ? h1s : h0s;
        short*       dst = (s&1) ? h0s : h1s;
        const short* xv  = xs8 + s*392;

        f32x4 acc[3][4];
        #pragma unroll
        for (int ti=0; ti<3; ++ti)
          #pragma unroll
          for (int gt=0; gt<4; ++gt) acc[ti][gt] = zero4;

        #pragma unroll
        for (int ti=0; ti<3; ++ti){
            if (mt0+ti == 5 && s >= 2) continue;   // tile-5 skip (wave-uniform)
            const int rbase = (mt0+ti)*16 + ln;
            #pragma unroll
            for (int kt=0; kt<6; ++kt){
                int tap = kt >> 1;
                bf16x8 a = *(const bf16x8*)(src + (rbase + tap)*72 + (kt&1)*32 + 8*g);
                #pragma unroll
                for (int gt=0; gt<4; ++gt)
                    acc[ti][gt] = __builtin_amdgcn_mfma_f32_16x16x32_bf16(a, Bf[kt][gt], acc[ti][gt], 0,0,0);
            }
            bf16x8 a6;
            #pragma unroll
            for (int i=0;i<8;++i) a6[i] = 0;
            if (g == 0){
                #pragma unroll
                for (int i=0;i<8;++i){ int tap = i/3, c = i - 3*tap; a6[i] = xv[(rbase+tap)*4 + c]; }
            } else if (g == 1){
                a6[0] = xv[(rbase+2)*4 + 2];
                a6[1] = (short)0x3F80;
            }
            #pragma unroll
            for (int gt=0; gt<4; ++gt)
                acc[ti][gt] = __builtin_amdgcn_mfma_f32_16x16x32_bf16(a6, Bf[6][gt], acc[ti][gt], 0,0,0);
        }

        // gates: m-index u stored at row u+1; valid rows [1+s, 83-s), l in [0,543)
        #pragma unroll
        for (int ti=0; ti<3; ++ti)
          #pragma unroll
          for (int rr=0; rr<4; ++rr){
            int row = (mt0+ti)*16 + 4*g + rr + 1;
            int l = l0 - 8 + row;
            if (row >= 1+s && row < 83-s && l >= 0 && l < L1_){
                float iv = fsig(acc[ti][0][rr]);
                float fv = fsig(acc[ti][1][rr]);
                float gv = fmaxf(acc[ti][2][rr], 0.f);
                float ov = fsig(acc[ti][3][rr]);
                float cv = fv*cr[ti][rr] + iv*gv;
                cr[ti][rr] = cv;
                float hv = ov * fmaxf(cv, 0.f);
                if (s < 7){
                    dst[row*72 + ch] = f2bf(hv);
                } else {
                    size_t idx = ((size_t)b*L1_ + l)*64 + ch;
                    c_out[idx] = cv;
                    h_out[idx] = (ushort_t)f2bf(hv);
                }
            }
          }
        if (s < 7) __syncthreads();
    }
}

// ================= Stage 2: ConvLSTM1D #2, MFMA, persistent, double-buffered (round-10/11 PASS verbatim) =================
__global__ __launch_bounds__(512) void lstm2_mfma(
    const ushort_t* __restrict__ x2, // (B,543,64) bf16
    const float* __restrict__ Wh2,   // (3,32,128)
    const float* __restrict__ Wx2,   // (3,1,128)
    const float* __restrict__ b2,    // (128)
    float* __restrict__ out)         // (B,64,32)
{
    __shared__ short hs[2][66*40];
    __shared__ short xs2[2][66];
    const int tid = threadIdx.x;
    const int wave = tid>>6, lane = tid&63, g = lane>>4, ln = lane&15;
    const int s = wave&3, q = wave>>2;
    const int b = blockIdx.x;

    bf16x8 Bf[4][4];
    #pragma unroll
    for (int gi=0; gi<4; ++gi){
        int j = (2*gi + q)*16 + ln;
        #pragma unroll
        for (int kt=0; kt<3; ++kt){
            bf16x8 o;
            #pragma unroll
            for (int i=0;i<8;++i) o[i] = f2bf(Wh2[(kt*32 + 8*g + i)*128 + j]);
            Bf[kt][gi] = o;
        }
        bf16x8 o;
        #pragma unroll
        for (int i=0;i<8;++i) o[i] = 0;
        if (g==0){
            o[0]=f2bf(Wx2[0*128+j]); o[1]=f2bf(Wx2[1*128+j]); o[2]=f2bf(Wx2[2*128+j]);
            o[3]=f2bf(b2[j]);
        }
        Bf[3][gi] = o;
    }

    const ushort_t* xb = x2 + (size_t)b*(T2_*64);

    for (int i=tid; i<2640; i+=512) ((int*)hs)[i] = 0;
    if (tid < 66){
        xs2[1][tid] = 0;
        short v = 0;
        if (tid >= 1 && tid < 65) v = (short)xb[tid - 1];
        xs2[0][tid] = v;
    }
    float creg[4];
    #pragma unroll
    for (int i=0;i<4;++i) creg[i]=0.f;

    ushort_t xreg = (tid < 64) ? xb[64 + tid] : (ushort_t)0;
    __syncthreads();

    const int lA = 16*s + ln;
    const int chn = 16*q + ln;

    for (int t=0; t<T2_; ++t){
        const int cur = t & 1, nxt = cur ^ 1;
        if (tid < 64 && t+1 < T2_) xs2[nxt][1+tid] = (short)xreg;
        if (tid < 64 && t+2 < T2_) xreg = xb[(size_t)(t+2)*64 + tid];

        f32x4 acc[4];
        f32x4 zero4 = {0.f,0.f,0.f,0.f};
        #pragma unroll
        for (int gi=0; gi<4; ++gi) acc[gi] = zero4;

        #pragma unroll
        for (int kt=0; kt<3; ++kt){
            bf16x8 a = *(const bf16x8*)(&hs[cur][0] + (lA + kt)*40 + 8*g);
            #pragma unroll
            for (int gi=0; gi<4; ++gi)
                acc[gi] = __builtin_amdgcn_mfma_f32_16x16x32_bf16(a, Bf[kt][gi], acc[gi], 0,0,0);
        }
        {
            bf16x8 a3;
            #pragma unroll
            for (int i=0;i<8;++i) a3[i] = 0;
            if (g==0){
                a3[0]=xs2[cur][lA]; a3[1]=xs2[cur][lA+1]; a3[2]=xs2[cur][lA+2];
                a3[3]=(short)0x3F80;
            }
            #pragma unroll
            for (int gi=0; gi<4; ++gi)
                acc[gi] = __builtin_amdgcn_mfma_f32_16x16x32_bf16(a3, Bf[3][gi], acc[gi], 0,0,0);
        }

        #pragma unroll
        for (int r=0; r<4; ++r){
            int l = 16*s + 4*g + r;
            float iv = fsig(acc[0][r]);
            float fv = fsig(acc[1][r]);
            float gv = fmaxf(acc[2][r], 0.f);
            float ov = fsig(acc[3][r]);
            float cv = fv*creg[r] + iv*gv;
            creg[r] = cv;
            float hv = ov * fmaxf(cv, 0.f);
            hs[nxt][(1+l)*40 + chn] = f2bf(hv);
            if (t == T2_-1) out[(size_t)b*2048 + l*32 + chn] = hv;
        }
        __syncthreads();
    }
}

// ================= Transformer decoder, 1 WG per batch =================
__global__ __launch_bounds__(256) void decoder_kernel(
    const float* __restrict__ xin,
    const float* __restrict__ Wq, const float* __restrict__ bq,
    const float* __restrict__ Wk, const float* __restrict__ bk,
    const float* __restrict__ Wv, const float* __restrict__ bv,
    const float* __restrict__ Wo, const float* __restrict__ bo,
    const float* __restrict__ g1, const float* __restrict__ be1,
    const float* __restrict__ W1, const float* __restrict__ bf1,
    const float* __restrict__ W2, const float* __restrict__ bf2,
    const float* __restrict__ g2, const float* __restrict__ be2,
    float* __restrict__ xout)
{
    __shared__ float smem[16384];
    float* sx  = smem;
    float* sq  = smem + 2048;
    float* sk  = smem + 4096;
    float* sv  = smem + 6144;
    float* so  = smem + 8192;
    float* sy  = smem + 10240;
    float* sff = smem + 12288;

    const int b = blockIdx.x;
    const int tid = threadIdx.x;

    for (int i=tid; i<2048; i+=256) sx[i] = xin[(size_t)b*2048 + i];
    __syncthreads();

    for (int i=tid; i<2048; i+=256){
        int s = i >> 5, j = i & 31;
        float aq = bq[j], ak = bk[j], av = bv[j];
        for (int d=0; d<32; ++d){
            float xv = sx[s*32+d];
            aq = fmaf(xv, Wq[d*32+j], aq);
            ak = fmaf(xv, Wk[d*32+j], ak);
            av = fmaf(xv, Wv[d*32+j], av);
        }
        sq[i]=aq; sk[i]=ak; sv[i]=av;
    }
    __syncthreads();

    if (tid < 128){
        int h = tid >> 6, si = tid & 63;
        const int o = h*16;
        float qv[16];
        #pragma unroll
        for (int kk=0; kk<16; ++kk) qv[kk] = sq[si*32 + o + kk];
        float mx = -1e30f;
        for (int ti=0; ti<=si; ++ti){
            float sc = 0.f;
            #pragma unroll
            for (int kk=0; kk<16; ++kk) sc = fmaf(qv[kk], sk[ti*32+o+kk], sc);
            mx = fmaxf(mx, sc*0.25f);
        }
        float sum = 0.f;
        float accv[16];
        #pragma unroll
        for (int kk=0; kk<16; ++kk) accv[kk]=0.f;
        for (int ti=0; ti<=si; ++ti){
            float sc = 0.f;
            #pragma unroll
            for (int kk=0; kk<16; ++kk) sc = fmaf(qv[kk], sk[ti*32+o+kk], sc);
            float p = expf(sc*0.25f - mx);
            sum += p;
            #pragma unroll
            for (int kk=0; kk<16; ++kk) accv[kk] = fmaf(p, sv[ti*32+o+kk], accv[kk]);
        }
        float inv = 1.f/sum;
        #pragma unroll
        for (int kk=0; kk<16; ++kk) so[si*32 + o + kk] = accv[kk]*inv;
    }
    __syncthreads();

    for (int i=tid; i<2048; i+=256){
        int s = i>>5, d = i&31;
        float a = bo[d];
        for (int j=0; j<32; ++j) a = fmaf(so[s*32+j], Wo[j*32+d], a);
        sy[i] = sx[i] + a;
    }
    __syncthreads();
    if (tid < 64){
        float mu=0.f;
        for (int d=0; d<32; ++d) mu += sy[tid*32+d];
        mu *= (1.f/32.f);
        float var=0.f;
        for (int d=0; d<32; ++d){ float dd = sy[tid*32+d]-mu; var = fmaf(dd,dd,var); }
        var *= (1.f/32.f);
        float rs = rsqrtf(var + 1e-5f);
        for (int d=0; d<32; ++d) sy[tid*32+d] = (sy[tid*32+d]-mu)*rs*g1[d] + be1[d];
    }
    __syncthreads();
    for (int i=tid; i<4096; i+=256){
        int s = i>>6, ff = i&63;
        float a = bf1[ff];
        for (int d=0; d<32; ++d) a = fmaf(sy[s*32+d], W1[d*64+ff], a);
        sff[i] = fmaxf(a, 0.f);
    }
    __syncthreads();
    for (int i=tid; i<2048; i+=256){
        int s=i>>5, d=i&31;
        float a = bf2[d];
        for (int ff=0; ff<64; ++ff) a = fmaf(sff[s*64+ff], W2[ff*32+d], a);
        sx[i] = sy[i] + a;
    }
    __syncthreads();
    if (tid < 64){
        float mu=0.f;
        for (int d=0; d<32; ++d) mu += sx[tid*32+d];
        mu *= (1.f/32.f);
        float var=0.f;
        for (int d=0; d<32; ++d){ float dd = sx[tid*32+d]-mu; var = fmaf(dd,dd,var); }
        var *= (1.f/32.f);
        float rs = rsqrtf(var + 1e-5f);
        for (int d=0; d<32; ++d)
            xout[(size_t)b*2048 + tid*32 + d] = (sx[tid*32+d]-mu)*rs*g2[d] + be2[d];
    }
}

// ================= Vocab head: 128-row x 1024-col tiles, float4 Wd/out, 512 WGs (2/CU) =================
// grid (32, 16), block 256. thread: 4 cols (float4 loads/stores), Wd cols in 128 regs.
__global__ __launch_bounds__(256) void head_kernel(
    const float* __restrict__ xin,  // (2048, 32)
    const float* __restrict__ Wd,   // (32, 32000)
    const float* __restrict__ bd,   // (32000)
    float* __restrict__ out)        // (2048, 32000)
{
    __shared__ float sx[128*32];    // 16 KB
    const int r0 = blockIdx.y * 128;
    const int c0 = blockIdx.x * 1024;
    const int tid = threadIdx.x;
    for (int u=tid; u<128*8; u+=256){
        int row = u>>3, c8 = u&7;
        *(float4*)(sx + row*32 + c8*4) = *(const float4*)(xin + (size_t)(r0+row)*32 + c8*4);
    }
    __syncthreads();
    int c = c0 + tid*4;
    if (c >= VOCAB_) return;         // VOCAB_%4==0 and c%4==0 -> full float4 or nothing
    float4 w[32];
    #pragma unroll
    for (int d=0; d<32; ++d) w[d] = *(const float4*)(Wd + (size_t)d*VOCAB_ + c);
    const float4 b4 = *(const float4*)(bd + c);
    for (int r=0; r<128; ++r){
        const float* xr = sx + r*32;
        float a0=b4.x, a1=b4.y, a2=b4.z, a3=b4.w;
        #pragma unroll
        for (int d=0; d<32; ++d){
            float xv = xr[d];      // same addr across lanes -> LDS broadcast
            a0 = fmaf(xv, w[d].x, a0);
            a1 = fmaf(xv, w[d].y, a1);
            a2 = fmaf(xv, w[d].z, a2);
            a3 = fmaf(xv, w[d].w, a3);
        }
        *reinterpret_cast<float4*>(&out[(size_t)(r0+r)*VOCAB_ + c]) = make_float4(a0,a1,a2,a3);
    }
}

// ================= launch =================
extern "C" void kernel_launch(void* const* d_in, const int* in_sizes, int n_in,
                              void* d_out, int out_size, void* d_ws, size_t ws_size,
                              hipStream_t stream)
{
    const float* x   = (const float*)d_in[0];
    const float* Wx1 = (const float*)d_in[1];
    const float* Wh1 = (const float*)d_in[2];
    const float* b1  = (const float*)d_in[3];
    const float* Wx2 = (const float*)d_in[4];
    const float* Wh2 = (const float*)d_in[5];
    const float* b2  = (const float*)d_in[6];
    const float* Wq  = (const float*)d_in[7];
    const float* bq  = (const float*)d_in[8];
    const float* Wk  = (const float*)d_in[9];
    const float* bk  = (const float*)d_in[10];
    const float* Wv  = (const float*)d_in[11];
    const float* bv  = (const float*)d_in[12];
    const float* Wo  = (const float*)d_in[13];
    const float* bo  = (const float*)d_in[14];
    const float* g1  = (const float*)d_in[15];
    const float* be1 = (const float*)d_in[16];
    const float* W1  = (const float*)d_in[17];
    const float* bf1 = (const float*)d_in[18];
    const float* W2  = (const float*)d_in[19];
    const float* bf2 = (const float*)d_in[20];
    const float* g2  = (const float*)d_in[21];
    const float* be2 = (const float*)d_in[22];
    const float* Wd  = (const float*)d_in[23];
    const float* bd  = (const float*)d_in[24];

    const size_t nH = (size_t)B_ * L1_ * 64;    // 1,112,064 elements per state buffer
    float* ws = (float*)d_ws;
    size_t ws_floats = ws_size / sizeof(float);
    float* x3 = ws;                          // 65536 floats
    float* x4 = ws + 65536;                  // 65536 floats
    short* Bp = (short*)(ws + 131072);       // 57344 shorts = 28672 floats
    const size_t base_f = 131072 + 28672;
    const size_t need_f = base_f + nH + 2*nH; // 2 bf16 bufs + 2 f32 bufs
    float* statebase;
    if (ws_floats >= need_f) statebase = ws + base_f;
    else                     statebase = (float*)d_out;    // 262MB scratch, consumed before head writes
    ushort_t* h1a = (ushort_t*)statebase;                  // nH bf16
    ushort_t* h1b = h1a + nH;                              // nH bf16
    float*    c1a = (float*)(h1b + nH);                    // nH f32
    float*    c1b = c1a + nH;                              // nH f32

    hipMemsetAsync(h1a, 0, nH*sizeof(ushort_t), stream);
    hipMemsetAsync(c1a, 0, nH*sizeof(float), stream);

    pack_B1<<<28, 256, 0, stream>>>(Wh1, Wx1, b1, Bp);

    ushort_t *hcur = h1a, *hnxt = h1b;
    float    *ccur = c1a, *cnxt = c1b;
    for (int t=0; t<T1_; t+=8){
        lstm1_step8_mfma<<<dim3(8, B_), 512, 0, stream>>>(x, Bp, hcur, hnxt, ccur, cnxt, t);
        ushort_t* th = hcur; hcur = hnxt; hnxt = th;
        float*    tc = ccur; ccur = cnxt; cnxt = tc;
    }
    lstm2_mfma<<<dim3(B_), 512, 0, stream>>>(hcur, Wh2, Wx2, b2, x3);
    decoder_kernel<<<dim3(B_), 256, 0, stream>>>(x3, Wq,bq,Wk,bk,Wv,bv,Wo,bo,
                                                 g1,be1,W1,bf1,W2,bf2,g2,be2, x4);
    head_kernel<<<dim3(32, 16), 256, 0, stream>>>(x4, Wd, bd, (float*)d_out);
}